// Round 4
// baseline (801.656 us; speedup 1.0000x reference)
//
#include <hip/hip_runtime.h>
#include <math.h>

// ---------------------------------------------------------------------------
// GraphSAGE (2x SAGEConv mean + FC + sigmoid) on MI355X.
// Pipeline:
//   0) cvt: x -> bf16 xh [N,128]; wprep: W -> split-bf16 (hi+lo) MFMA B-frags
//   1) merged degree histogram: node counts + per-(group,bucket) counts
//      (group = blockIdx&7 ~ XCD; substream partitioning kills the 13x
//       write-amp seen in round-3 k_binA: 173 MB WRITE for 12.8 MB payload)
//   2) exclusive scan -> CSR offsets; bcur2: per-(group,bucket) cursors
//   3) binA: scatter packed (dst&15)<<17|src into XCD-local bucket substreams
//      binB: wave-per-bucket, LDS per-node cursors -> exact CSR slot
//   4) agg128: mean-aggregate xh over neighbors -> M [N,128] bf16
//   5) mm<8,2A,relu>: H1b = relu([M|xh] @ [W1l;W1r] + b1)  bf16, MFMA
//   6) mm<4,1A,->   : Ph  = H1b @ [W2l|W2r]                bf16, MFMA
//      (split-bf16 weights: W = Whi + Wlo, 2 accumulating MFMAs -> weight
//       error ~fp32; output error dominated by bf16 activations ~1e-3)
//   7) final: per node, mean-aggregate Ph[:,0:64], add Ph[n,64:]+b2, relu,
//      dot Wfc, sigmoid -> out[n]
// Uses mean(h1)@W2l == mean(h1@W2l) to halve layer-2 gather bytes.
// ---------------------------------------------------------------------------

typedef __attribute__((ext_vector_type(8))) short bf16x8;
typedef __attribute__((ext_vector_type(4))) float f32x4;

__device__ __forceinline__ unsigned bf16_rne(float f) {
  unsigned u = __float_as_uint(f);
  return (u + 0x7FFFu + ((u >> 16) & 1u)) >> 16;
}
__device__ __forceinline__ unsigned pack2(float a, float b) {
  return bf16_rne(a) | (bf16_rne(b) << 16);
}
__device__ __forceinline__ float bf16lo(unsigned u) { return __uint_as_float(u << 16); }
__device__ __forceinline__ float bf16hi(unsigned u) { return __uint_as_float(u & 0xFFFF0000u); }
__device__ __forceinline__ float bf16s(unsigned short v) { return __uint_as_float(((unsigned)v) << 16); }

// x fp32 -> xh bf16 (packed pairs)
__global__ __launch_bounds__(256) void k_cvt(const float2* __restrict__ x,
                                             unsigned* __restrict__ xh, int n2) {
  int stride = gridDim.x * 256;
  for (int i = blockIdx.x * 256 + threadIdx.x; i < n2; i += stride) {
    float2 v = x[i];
    xh[i] = pack2(v.x, v.y);
  }
}

// W (fp32) -> split-bf16 B-fragments in MFMA order:
// p[((kt*8+ct)*64 + lane)*8 + j] = W[kt*32 + (lane>>4)*8 + j][ct*16 + (lane&15)]
// layer1: Wcat = [W1l ; W1r] (256x128), kt 0..7  -> p1h/p1l (32768 shorts)
// layer2: Wcat = [W2l | W2r] (128x128), kt 0..3  -> p2h/p2l (16384 shorts)
__global__ __launch_bounds__(256) void k_wprep(const float* __restrict__ W1l,
                                               const float* __restrict__ W1r,
                                               const float* __restrict__ W2l,
                                               const float* __restrict__ W2r,
                                               unsigned short* __restrict__ p1h,
                                               unsigned short* __restrict__ p1l,
                                               unsigned short* __restrict__ p2h,
                                               unsigned short* __restrict__ p2l) {
  int idx = blockIdx.x * 256 + threadIdx.x;
  if (idx < 32768) {
    int j = idx & 7, l = (idx >> 3) & 63, ct = (idx >> 9) & 7, kt = idx >> 12;
    int k = kt * 32 + (l >> 4) * 8 + j;
    int c = ct * 16 + (l & 15);
    float wv = (k < 128) ? W1l[k * 128 + c] : W1r[(k - 128) * 128 + c];
    unsigned short hi = (unsigned short)bf16_rne(wv);
    float hif = __uint_as_float(((unsigned)hi) << 16);
    unsigned short lo = (unsigned short)bf16_rne(wv - hif);
    p1h[idx] = hi; p1l[idx] = lo;
  } else if (idx < 49152) {
    int i2 = idx - 32768;
    int j = i2 & 7, l = (i2 >> 3) & 63, ct = (i2 >> 9) & 7, kt = i2 >> 12;
    int k = kt * 32 + (l >> 4) * 8 + j;
    int c = ct * 16 + (l & 15);
    float wv = (c < 64) ? W2l[k * 64 + c] : W2r[k * 64 + (c - 64)];
    unsigned short hi = (unsigned short)bf16_rne(wv);
    float hif = __uint_as_float(((unsigned)hi) << 16);
    unsigned short lo = (unsigned short)bf16_rne(wv - hif);
    p2h[i2] = hi; p2l[i2] = lo;
  }
}

// merged: node-degree histogram + per-(group,bucket) histogram.
// MUST use same grid + grid-stride partition as k_binA so groups match.
__global__ __launch_bounds__(256) void k_count(const int* __restrict__ dst,
                                               int* __restrict__ cnt,
                                               int* __restrict__ cnt2,
                                               int NB, int E) {
  int g = blockIdx.x & 7;
  int stride = gridDim.x * blockDim.x;
  for (int e = blockIdx.x * blockDim.x + threadIdx.x; e < E; e += stride) {
    int d = dst[e];
    atomicAdd(&cnt[d], 1);
    atomicAdd(&cnt2[g * NB + (d >> 4)], 1);
  }
}

__global__ __launch_bounds__(256) void k_scan_block(const int* __restrict__ cnt,
                                                    int* __restrict__ off,
                                                    int* __restrict__ bsum, int n) {
  __shared__ int sh[256];
  int t = threadIdx.x;
  int i = blockIdx.x * 256 + t;
  int v = (i < n) ? cnt[i] : 0;
  sh[t] = v;
  __syncthreads();
  int x = v;
  for (int d = 1; d < 256; d <<= 1) {
    int y = (t >= d) ? sh[t - d] : 0;
    __syncthreads();
    x += y;
    sh[t] = x;
    __syncthreads();
  }
  if (i < n) off[i] = x - v;
  if (t == 255) bsum[blockIdx.x] = x;
}

__global__ void k_scan_partials(int* bsum, int nb) {
  __shared__ int sh[512];
  int t = threadIdx.x;
  int v = (t < nb) ? bsum[t] : 0;
  sh[t] = v;
  __syncthreads();
  int x = v;
  for (int d = 1; d < 512; d <<= 1) {
    int y = (t >= d) ? sh[t - d] : 0;
    __syncthreads();
    x += y;
    sh[t] = x;
    __syncthreads();
  }
  if (t < nb) bsum[t] = x - v;
}

__global__ __launch_bounds__(256) void k_scan_add(int* __restrict__ off,
                                                  const int* __restrict__ bsum,
                                                  int n, int total) {
  int i = blockIdx.x * 256 + threadIdx.x;
  if (i < n) off[i] += bsum[blockIdx.x];
  if (i == 0) off[n] = total;
}

// per-(group,bucket) cursors, group-major (no cross-group line sharing)
__global__ __launch_bounds__(256) void k_bcur2(const int* __restrict__ off,
                                               const int* __restrict__ cnt2,
                                               int* __restrict__ bcur2, int NB) {
  int b = blockIdx.x * 256 + threadIdx.x;
  if (b >= NB) return;
  int base = off[b * 16];
#pragma unroll
  for (int g = 0; g < 8; ++g) {
    bcur2[g * NB + b] = base;
    base += cnt2[g * NB + b];
  }
}

// pass A: scatter packed entries into XCD-local bucket substreams
__global__ __launch_bounds__(256) void k_binA(const int* __restrict__ src,
                                              const int* __restrict__ dst,
                                              int* __restrict__ bcur2,
                                              unsigned* __restrict__ tmp,
                                              int NB, int E) {
  int g = blockIdx.x & 7;
  int stride = gridDim.x * blockDim.x;
  for (int e = blockIdx.x * blockDim.x + threadIdx.x; e < E; e += stride) {
    int d = dst[e];
    int p = atomicAdd(&bcur2[g * NB + (d >> 4)], 1);
    tmp[p] = (unsigned)src[e] | ((unsigned)(d & 15) << 17); // src < 2^17
  }
}

// pass B: wave per bucket; 16 per-node cursors in LDS; order-agnostic placement
__global__ __launch_bounds__(256) void k_binB(const unsigned* __restrict__ tmp,
                                              const int* __restrict__ off,
                                              int* __restrict__ csr,
                                              int NB, int N) {
  __shared__ int c[4][16];
  int w = threadIdx.x >> 6;
  int lane = threadIdx.x & 63;
  int wid = blockIdx.x * 4 + w;
  if (wid >= NB) return;
  int n0 = wid * 16;
  int nend = min(n0 + 16, N);
  int s = off[n0], e = off[nend];
  if (lane < nend - n0) c[w][lane] = off[n0 + lane];
  __builtin_amdgcn_wave_barrier();
  for (int i = s + lane; i < e; i += 64) {
    unsigned v = tmp[i];
    int srcv = (int)(v & 0x1FFFFu);
    int dlow = (int)(v >> 17);
    int pos = atomicAdd(&c[w][dlow], 1);
    csr[pos] = srcv;
  }
}

// wave-per-node mean aggregation of bf16 128-dim rows -> M (bf16)
__global__ __launch_bounds__(256) void k_agg128(const unsigned* __restrict__ xh,
                                                const int* __restrict__ off,
                                                const int* __restrict__ csr,
                                                unsigned* __restrict__ M, int n) {
  int lane = threadIdx.x & 63;
  int node = blockIdx.x * 4 + (threadIdx.x >> 6);
  if (node >= n) return;
  int s = off[node], e = off[node + 1];
  float ax0 = 0, ay0 = 0, ax1 = 0, ay1 = 0, ax2 = 0, ay2 = 0, ax3 = 0, ay3 = 0;
  int i = s;
  for (; i + 4 <= e; i += 4) {
    int s0 = csr[i], s1 = csr[i + 1], s2 = csr[i + 2], s3 = csr[i + 3];
    unsigned u0 = xh[(size_t)s0 * 64 + lane];
    unsigned u1 = xh[(size_t)s1 * 64 + lane];
    unsigned u2 = xh[(size_t)s2 * 64 + lane];
    unsigned u3 = xh[(size_t)s3 * 64 + lane];
    ax0 += bf16lo(u0); ay0 += bf16hi(u0);
    ax1 += bf16lo(u1); ay1 += bf16hi(u1);
    ax2 += bf16lo(u2); ay2 += bf16hi(u2);
    ax3 += bf16lo(u3); ay3 += bf16hi(u3);
  }
  for (; i < e; ++i) {
    unsigned u0 = xh[(size_t)csr[i] * 64 + lane];
    ax0 += bf16lo(u0); ay0 += bf16hi(u0);
  }
  int deg = e - s;
  float inv = 1.0f / (float)(deg > 0 ? deg : 1);
  float rx = (ax0 + ax1 + ax2 + ax3) * inv;
  float ry = (ay0 + ay1 + ay2 + ay3) * inv;
  M[(size_t)node * 64 + lane] = pack2(rx, ry);
}

// MFMA GEMM: C(bf16)[N,128] = act(A @ W + bias)
// 1 wave = 16 rows x 128 cols; block = 4 waves = 64 rows. A read direct from
// global (bf16, row-major, [N,128] per table). W from prepped split-bf16
// frags (hi then lo, both accumulate). KSTEPS = K/32.
// TWOA: kt < KSTEPS/2 reads A0, else A1 (Wcat stacked accordingly).
// Layouts (CDNA4 16x16x32): A row=l&15, k=(l>>4)*8+j; B col=l&15, same k;
// D col=l&15, row=(l>>4)*4+reg  [m89-verified].
template <int KSTEPS, bool TWOA, bool RELU>
__global__ __launch_bounds__(256) void k_mm(const unsigned short* __restrict__ A0,
                                            const unsigned short* __restrict__ A1,
                                            const unsigned short* __restrict__ Bh,
                                            const unsigned short* __restrict__ Bl,
                                            const float* __restrict__ bias,
                                            unsigned short* __restrict__ C, int N) {
  int l = threadIdx.x & 63, wv = threadIdx.x >> 6;
  int rb = blockIdx.x * 64 + wv * 16;
  int arow = rb + (l & 15);
  if (arow > N - 1) arow = N - 1;                     // clamp: loads stay in-bounds
  const size_t aoff = (size_t)arow * 128 + ((l >> 4) * 8);
  f32x4 acc[8] = {};
  float bs[8];
  if (RELU) {
#pragma unroll
    for (int ct = 0; ct < 8; ++ct) bs[ct] = bias[ct * 16 + (l & 15)];
  }
#pragma unroll 2
  for (int kt = 0; kt < KSTEPS; ++kt) {
    const unsigned short* At = TWOA ? (kt < KSTEPS / 2 ? A0 : A1) : A0;
    int ko = TWOA ? (kt < KSTEPS / 2 ? kt : kt - KSTEPS / 2) : kt;
    bf16x8 a = *(const bf16x8*)(At + aoff + (size_t)ko * 32);
#pragma unroll
    for (int ct = 0; ct < 8; ++ct) {
      bf16x8 bh = *(const bf16x8*)(Bh + (((size_t)(kt * 8 + ct) * 64 + l) * 8));
      bf16x8 bl = *(const bf16x8*)(Bl + (((size_t)(kt * 8 + ct) * 64 + l) * 8));
      acc[ct] = __builtin_amdgcn_mfma_f32_16x16x32_bf16(a, bh, acc[ct], 0, 0, 0);
      acc[ct] = __builtin_amdgcn_mfma_f32_16x16x32_bf16(a, bl, acc[ct], 0, 0, 0);
    }
  }
  int r0 = rb + (l >> 4) * 4;
  int col = l & 15;
#pragma unroll
  for (int ct = 0; ct < 8; ++ct) {
#pragma unroll
    for (int r = 0; r < 4; ++r) {
      int row = r0 + r;
      if (row < N) {
        float v = acc[ct][r];
        if (RELU) v = fmaxf(v + bs[ct], 0.f);
        C[(size_t)row * 128 + ct * 16 + col] = (unsigned short)bf16_rne(v);
      }
    }
  }
}

// wave-per-node: mean-aggregate Ph[:,0:64] (bf16), add Ph[n,64:]+b2, relu,
// dot Wfc, sigmoid
__global__ __launch_bounds__(256) void k_final(const unsigned short* __restrict__ Ph,
                                               const int* __restrict__ off,
                                               const int* __restrict__ csr,
                                               const float* __restrict__ b2,
                                               const float* __restrict__ Wfc,
                                               const float* __restrict__ bfc,
                                               float* __restrict__ out, int n) {
  int lane = threadIdx.x & 63;
  int node = blockIdx.x * 4 + (threadIdx.x >> 6);
  if (node >= n) return;
  int s = off[node], e = off[node + 1];
  float a0 = 0, a1 = 0, a2 = 0, a3 = 0;
  int i = s;
  for (; i + 4 <= e; i += 4) {
    int s0 = csr[i], s1 = csr[i + 1], s2 = csr[i + 2], s3 = csr[i + 3];
    a0 += bf16s(Ph[(size_t)s0 * 128 + lane]);
    a1 += bf16s(Ph[(size_t)s1 * 128 + lane]);
    a2 += bf16s(Ph[(size_t)s2 * 128 + lane]);
    a3 += bf16s(Ph[(size_t)s3 * 128 + lane]);
  }
  for (; i < e; ++i) a0 += bf16s(Ph[(size_t)csr[i] * 128 + lane]);
  int deg = e - s;
  float inv = 1.0f / (float)(deg > 0 ? deg : 1);
  float h = (a0 + a1 + a2 + a3) * inv + bf16s(Ph[(size_t)node * 128 + 64 + lane]) + b2[lane];
  h = fmaxf(h, 0.f);
  float v = h * Wfc[lane];
#pragma unroll
  for (int o2 = 32; o2 > 0; o2 >>= 1) v += __shfl_xor(v, o2, 64);
  if (lane == 0) out[node] = 1.0f / (1.0f + expf(-(v + bfc[0])));
}

extern "C" void kernel_launch(void* const* d_in, const int* in_sizes, int n_in,
                              void* d_out, int out_size, void* d_ws, size_t ws_size,
                              hipStream_t stream) {
  const float* x   = (const float*)d_in[0];
  const int*   ei  = (const int*)d_in[1];
  const float* W1l = (const float*)d_in[2];
  const float* b1  = (const float*)d_in[3];
  const float* W1r = (const float*)d_in[4];
  const float* W2l = (const float*)d_in[5];
  const float* b2  = (const float*)d_in[6];
  const float* W2r = (const float*)d_in[7];
  const float* Wfc = (const float*)d_in[8];
  const float* bfc = (const float*)d_in[9];
  float* out = (float*)d_out;

  const int N = in_sizes[0] / 128;
  const int E = in_sizes[1] / 2;
  const int* srcp = ei;       // edge_index[0]
  const int* dstp = ei + E;   // edge_index[1]
  const int NB = (N + 15) / 16;

  // workspace layout (256B aligned regions), ~92 MB total
  char* w = (char*)d_ws;
  auto alloc = [&](size_t bytes) -> void* {
    void* p = (void*)w;
    w += (bytes + 255) & ~(size_t)255;
    return p;
  };
  int*            off   = (int*)alloc((size_t)(N + 1) * 4);
  int*            cur   = (int*)alloc((size_t)N * 4);
  int*            bsum  = (int*)alloc(4096);
  int*            cnt2  = (int*)alloc((size_t)8 * NB * 4);
  int*            bcur2 = (int*)alloc((size_t)8 * NB * 4);
  int*            csr   = (int*)alloc((size_t)E * 4);
  unsigned*       xh    = (unsigned*)alloc((size_t)N * 64 * 4);  // bf16 x
  unsigned*       M     = (unsigned*)alloc((size_t)N * 64 * 4);  // bf16 agg; later Ph
  unsigned short* H1b   = (unsigned short*)alloc((size_t)N * 128 * 2);
  unsigned short* p1h   = (unsigned short*)alloc(32768 * 2);
  unsigned short* p1l   = (unsigned short*)alloc(32768 * 2);
  unsigned short* p2h   = (unsigned short*)alloc(16384 * 2);
  unsigned short* p2l   = (unsigned short*)alloc(16384 * 2);
  unsigned* tmp = (unsigned*)H1b;  // lifetimes disjoint: tmp dead before k_mm<8> writes H1b
  unsigned short* Ph = (unsigned short*)M;  // M dead after k_mm<8> reads it

  const int nb = (N + 255) / 256; // <= 512 (k_scan_partials capacity)

  hipMemsetAsync(cur, 0, (size_t)N * 4, stream);
  hipMemsetAsync(cnt2, 0, (size_t)8 * NB * 4, stream);
  k_cvt<<<1024, 256, 0, stream>>>((const float2*)x, xh, N * 64);
  k_wprep<<<192, 256, 0, stream>>>(W1l, W1r, W2l, W2r, p1h, p1l, p2h, p2l);
  k_count<<<2048, 256, 0, stream>>>(dstp, cur, cnt2, NB, E);
  k_scan_block<<<nb, 256, 0, stream>>>(cur, off, bsum, N);
  k_scan_partials<<<1, 512, 0, stream>>>(bsum, nb);
  k_scan_add<<<nb, 256, 0, stream>>>(off, bsum, N, E);
  k_bcur2<<<(NB + 255) / 256, 256, 0, stream>>>(off, cnt2, bcur2, NB);
  k_binA<<<2048, 256, 0, stream>>>(srcp, dstp, bcur2, tmp, NB, E);
  k_binB<<<(NB + 3) / 4, 256, 0, stream>>>(tmp, off, csr, NB, N);
  k_agg128<<<(N + 3) / 4, 256, 0, stream>>>(xh, off, csr, M, N);
  k_mm<8, true, true><<<(N + 63) / 64, 256, 0, stream>>>(
      (const unsigned short*)M, (const unsigned short*)xh, p1h, p1l, b1, H1b, N);
  k_mm<4, false, false><<<(N + 63) / 64, 256, 0, stream>>>(
      H1b, nullptr, p2h, p2l, nullptr, Ph, N);
  k_final<<<(N + 3) / 4, 256, 0, stream>>>(Ph, off, csr, b2, Wfc, bfc, out, N);
}

// Round 5
// 656.001 us; speedup vs baseline: 1.2220x; 1.2220x over previous
//
#include <hip/hip_runtime.h>
#include <math.h>

// ---------------------------------------------------------------------------
// GraphSAGE (2x SAGEConv mean + FC + sigmoid) on MI355X.
//
// Round-5 insight: per-edge device-scope atomics write ~32B through TCC each
// (round-4 k_count: 196 MB WRITE for 600 KB of counters, 244 us). CSR build
// is now an all-LDS radix partition with ZERO per-edge global atomics:
//   1) k_hist: 64 blocks, chunk-partitioned edges, LDS bucket histogram
//      (bucket = dst>>4, NB=6250), plain coalesced flush -> histG[64][NB]
//   2) k_btot + 3-kernel scan over NB + k_scur -> boff[], S2[64][NB]
//      (per-(block,bucket) slice starts in tmp)
//   3) k_binA: same partition, LDS cursors from S2 -> tmp[pos] plain stores
//   4) k_binB: wave-per-bucket; count pass (16 LDS node counters) -> local
//      scan writes off[] (no 100K scan needed!); place pass -> exact CSR slot
//   5) agg128: mean-aggregate xh (bf16) over neighbors -> M [N,128] bf16
//   6) mm<8,2A,relu>: H1b = relu([M|xh] @ [W1l;W1r] + b1)  bf16 MFMA
//   7) mm<4,1A,->   : Ph  = H1b @ [W2l|W2r]                bf16 MFMA
//      (split-bf16 weights: W = Whi + Wlo, 2 accumulating MFMAs)
//   8) final: mean-aggregate Ph[:,0:64], + Ph[n,64:]+b2, relu, dot Wfc,
//      sigmoid -> out[n]
// Uses mean(h1)@W2l == mean(h1@W2l) to halve layer-2 gather bytes.
// ---------------------------------------------------------------------------

#define B_PART 64     // blocks in hist/binA (must match: S2 is per-block)
#define CHUNK 1024    // edge chunk size for the block partition
#define NB_MAX 6400   // LDS bucket capacity (N <= 102400)

typedef __attribute__((ext_vector_type(8))) short bf16x8;
typedef __attribute__((ext_vector_type(4))) float f32x4;

__device__ __forceinline__ unsigned bf16_rne(float f) {
  unsigned u = __float_as_uint(f);
  return (u + 0x7FFFu + ((u >> 16) & 1u)) >> 16;
}
__device__ __forceinline__ unsigned pack2(float a, float b) {
  return bf16_rne(a) | (bf16_rne(b) << 16);
}
__device__ __forceinline__ float bf16lo(unsigned u) { return __uint_as_float(u << 16); }
__device__ __forceinline__ float bf16hi(unsigned u) { return __uint_as_float(u & 0xFFFF0000u); }
__device__ __forceinline__ float bf16s(unsigned short v) { return __uint_as_float(((unsigned)v) << 16); }

// x fp32 -> xh bf16 (packed pairs)
__global__ __launch_bounds__(256) void k_cvt(const float2* __restrict__ x,
                                             unsigned* __restrict__ xh, int n2) {
  int stride = gridDim.x * 256;
  for (int i = blockIdx.x * 256 + threadIdx.x; i < n2; i += stride) {
    float2 v = x[i];
    xh[i] = pack2(v.x, v.y);
  }
}

// W (fp32) -> split-bf16 B-fragments in MFMA order:
// p[((kt*8+ct)*64 + lane)*8 + j] = Wcat[kt*32 + (lane>>4)*8 + j][ct*16 + (lane&15)]
__global__ __launch_bounds__(256) void k_wprep(const float* __restrict__ W1l,
                                               const float* __restrict__ W1r,
                                               const float* __restrict__ W2l,
                                               const float* __restrict__ W2r,
                                               unsigned short* __restrict__ p1h,
                                               unsigned short* __restrict__ p1l,
                                               unsigned short* __restrict__ p2h,
                                               unsigned short* __restrict__ p2l) {
  int idx = blockIdx.x * 256 + threadIdx.x;
  if (idx < 32768) {
    int j = idx & 7, l = (idx >> 3) & 63, ct = (idx >> 9) & 7, kt = idx >> 12;
    int k = kt * 32 + (l >> 4) * 8 + j;
    int c = ct * 16 + (l & 15);
    float wv = (k < 128) ? W1l[k * 128 + c] : W1r[(k - 128) * 128 + c];
    unsigned short hi = (unsigned short)bf16_rne(wv);
    float hif = __uint_as_float(((unsigned)hi) << 16);
    unsigned short lo = (unsigned short)bf16_rne(wv - hif);
    p1h[idx] = hi; p1l[idx] = lo;
  } else if (idx < 49152) {
    int i2 = idx - 32768;
    int j = i2 & 7, l = (i2 >> 3) & 63, ct = (i2 >> 9) & 7, kt = i2 >> 12;
    int k = kt * 32 + (l >> 4) * 8 + j;
    int c = ct * 16 + (l & 15);
    float wv = (c < 64) ? W2l[k * 64 + c] : W2r[k * 64 + (c - 64)];
    unsigned short hi = (unsigned short)bf16_rne(wv);
    float hif = __uint_as_float(((unsigned)hi) << 16);
    unsigned short lo = (unsigned short)bf16_rne(wv - hif);
    p2h[i2] = hi; p2l[i2] = lo;
  }
}

// 1) per-block LDS bucket histogram; coalesced flush (no global atomics)
__global__ __launch_bounds__(256) void k_hist(const int* __restrict__ dst,
                                              int* __restrict__ histG,
                                              int NB, int E) {
  __shared__ int h[NB_MAX];
  for (int i = threadIdx.x; i < NB; i += 256) h[i] = 0;
  __syncthreads();
  for (int c = blockIdx.x; c * CHUNK < E; c += gridDim.x) {
    int e0 = c * CHUNK, e1 = min(e0 + CHUNK, E);
    for (int e = e0 + threadIdx.x; e < e1; e += 256)
      atomicAdd(&h[dst[e] >> 4], 1);
  }
  __syncthreads();
  for (int i = threadIdx.x; i < NB; i += 256) histG[blockIdx.x * NB + i] = h[i];
}

// bucket totals (sum over B_PART rows; coalesced per-row slices)
__global__ __launch_bounds__(256) void k_btot(const int* __restrict__ histG,
                                              int* __restrict__ btot, int NB) {
  int b = blockIdx.x * 256 + threadIdx.x;
  if (b >= NB) return;
  int s = 0;
  for (int k = 0; k < B_PART; ++k) s += histG[k * NB + b];
  btot[b] = s;
}

__global__ __launch_bounds__(256) void k_scan_block(const int* __restrict__ cnt,
                                                    int* __restrict__ off,
                                                    int* __restrict__ bsum, int n) {
  __shared__ int sh[256];
  int t = threadIdx.x;
  int i = blockIdx.x * 256 + t;
  int v = (i < n) ? cnt[i] : 0;
  sh[t] = v;
  __syncthreads();
  int x = v;
  for (int d = 1; d < 256; d <<= 1) {
    int y = (t >= d) ? sh[t - d] : 0;
    __syncthreads();
    x += y;
    sh[t] = x;
    __syncthreads();
  }
  if (i < n) off[i] = x - v;
  if (t == 255) bsum[blockIdx.x] = x;
}

__global__ void k_scan_partials(int* bsum, int nb) {
  __shared__ int sh[512];
  int t = threadIdx.x;
  int v = (t < nb) ? bsum[t] : 0;
  sh[t] = v;
  __syncthreads();
  int x = v;
  for (int d = 1; d < 512; d <<= 1) {
    int y = (t >= d) ? sh[t - d] : 0;
    __syncthreads();
    x += y;
    sh[t] = x;
    __syncthreads();
  }
  if (t < nb) bsum[t] = x - v;
}

__global__ __launch_bounds__(256) void k_scan_add(int* __restrict__ off,
                                                  const int* __restrict__ bsum,
                                                  int n, int total) {
  int i = blockIdx.x * 256 + threadIdx.x;
  if (i < n) off[i] += bsum[blockIdx.x];
  if (i == 0) off[n] = total;
}

// per-(block,bucket) slice starts: S2[k][b] = boff[b] + sum_{k'<k} histG[k'][b]
__global__ __launch_bounds__(256) void k_scur(const int* __restrict__ boff,
                                              const int* __restrict__ histG,
                                              int* __restrict__ S2, int NB) {
  int b = blockIdx.x * 256 + threadIdx.x;
  if (b >= NB) return;
  int run = boff[b];
  for (int k = 0; k < B_PART; ++k) {
    S2[k * NB + b] = run;
    run += histG[k * NB + b];
  }
}

// 3) scatter into private per-(block,bucket) slices; LDS cursors only
__global__ __launch_bounds__(256) void k_binA(const int* __restrict__ src,
                                              const int* __restrict__ dst,
                                              const int* __restrict__ S2,
                                              unsigned* __restrict__ tmp,
                                              int NB, int E) {
  __shared__ int cur[NB_MAX];
  for (int i = threadIdx.x; i < NB; i += 256) cur[i] = S2[blockIdx.x * NB + i];
  __syncthreads();
  for (int c = blockIdx.x; c * CHUNK < E; c += gridDim.x) {
    int e0 = c * CHUNK, e1 = min(e0 + CHUNK, E);
    for (int e = e0 + threadIdx.x; e < e1; e += 256) {
      int d = dst[e];
      int p = atomicAdd(&cur[d >> 4], 1);
      tmp[p] = (unsigned)src[e] | ((unsigned)(d & 15) << 17); // src < 2^17
    }
  }
}

// 4) wave-per-bucket: count pass -> node offsets off[] (local 16-scan);
//    place pass -> exact CSR slot. Second tmp read is L2-hot.
__global__ __launch_bounds__(256) void k_binB(const unsigned* __restrict__ tmp,
                                              const int* __restrict__ boff,
                                              int* __restrict__ off,
                                              int* __restrict__ csr,
                                              int NB, int N, int E) {
  __shared__ int c[4][16];
  int w = threadIdx.x >> 6, lane = threadIdx.x & 63;
  int b = blockIdx.x * 4 + w;
  bool active = (b < NB);
  int s = 0, e = 0;
  if (active) { s = boff[b]; e = boff[b + 1]; }
  if (active && lane < 16) c[w][lane] = 0;
  __syncthreads();
  if (active)
    for (int i = s + lane; i < e; i += 64) atomicAdd(&c[w][tmp[i] >> 17], 1);
  __syncthreads();
  if (active && lane == 0) {
    int run = s, n0 = b * 16;
    for (int i = 0; i < 16; ++i) {
      int v = c[w][i];
      c[w][i] = run;
      if (n0 + i < N) off[n0 + i] = run;
      run += v;
    }
    if (b == NB - 1) off[N] = E;
  }
  __syncthreads();
  if (active)
    for (int i = s + lane; i < e; i += 64) {
      unsigned v = tmp[i];
      int pos = atomicAdd(&c[w][v >> 17], 1);
      csr[pos] = (int)(v & 0x1FFFFu);
    }
}

// wave-per-node mean aggregation of bf16 128-dim rows -> M (bf16)
__global__ __launch_bounds__(256) void k_agg128(const unsigned* __restrict__ xh,
                                                const int* __restrict__ off,
                                                const int* __restrict__ csr,
                                                unsigned* __restrict__ M, int n) {
  int lane = threadIdx.x & 63;
  int node = blockIdx.x * 4 + (threadIdx.x >> 6);
  if (node >= n) return;
  int s = off[node], e = off[node + 1];
  float ax0 = 0, ay0 = 0, ax1 = 0, ay1 = 0, ax2 = 0, ay2 = 0, ax3 = 0, ay3 = 0;
  int i = s;
  for (; i + 4 <= e; i += 4) {
    int s0 = csr[i], s1 = csr[i + 1], s2 = csr[i + 2], s3 = csr[i + 3];
    unsigned u0 = xh[(size_t)s0 * 64 + lane];
    unsigned u1 = xh[(size_t)s1 * 64 + lane];
    unsigned u2 = xh[(size_t)s2 * 64 + lane];
    unsigned u3 = xh[(size_t)s3 * 64 + lane];
    ax0 += bf16lo(u0); ay0 += bf16hi(u0);
    ax1 += bf16lo(u1); ay1 += bf16hi(u1);
    ax2 += bf16lo(u2); ay2 += bf16hi(u2);
    ax3 += bf16lo(u3); ay3 += bf16hi(u3);
  }
  for (; i < e; ++i) {
    unsigned u0 = xh[(size_t)csr[i] * 64 + lane];
    ax0 += bf16lo(u0); ay0 += bf16hi(u0);
  }
  int deg = e - s;
  float inv = 1.0f / (float)(deg > 0 ? deg : 1);
  float rx = (ax0 + ax1 + ax2 + ax3) * inv;
  float ry = (ay0 + ay1 + ay2 + ay3) * inv;
  M[(size_t)node * 64 + lane] = pack2(rx, ry);
}

// MFMA GEMM: C(bf16)[N,128] = act(A @ W + bias); 1 wave = 16 rows x 128 cols.
// Layouts (CDNA4 16x16x32): A row=l&15, k=(l>>4)*8+j; B col=l&15, same k;
// D col=l&15, row=(l>>4)*4+reg  [m89-verified].
template <int KSTEPS, bool TWOA, bool RELU>
__global__ __launch_bounds__(256) void k_mm(const unsigned short* __restrict__ A0,
                                            const unsigned short* __restrict__ A1,
                                            const unsigned short* __restrict__ Bh,
                                            const unsigned short* __restrict__ Bl,
                                            const float* __restrict__ bias,
                                            unsigned short* __restrict__ C, int N) {
  int l = threadIdx.x & 63, wv = threadIdx.x >> 6;
  int rb = blockIdx.x * 64 + wv * 16;
  int arow = rb + (l & 15);
  if (arow > N - 1) arow = N - 1;                     // clamp: loads stay in-bounds
  const size_t aoff = (size_t)arow * 128 + ((l >> 4) * 8);
  f32x4 acc[8] = {};
  float bs[8];
  if (RELU) {
#pragma unroll
    for (int ct = 0; ct < 8; ++ct) bs[ct] = bias[ct * 16 + (l & 15)];
  }
#pragma unroll 2
  for (int kt = 0; kt < KSTEPS; ++kt) {
    const unsigned short* At = TWOA ? (kt < KSTEPS / 2 ? A0 : A1) : A0;
    int ko = TWOA ? (kt < KSTEPS / 2 ? kt : kt - KSTEPS / 2) : kt;
    bf16x8 a = *(const bf16x8*)(At + aoff + (size_t)ko * 32);
#pragma unroll
    for (int ct = 0; ct < 8; ++ct) {
      bf16x8 bh = *(const bf16x8*)(Bh + (((size_t)(kt * 8 + ct) * 64 + l) * 8));
      bf16x8 bl = *(const bf16x8*)(Bl + (((size_t)(kt * 8 + ct) * 64 + l) * 8));
      acc[ct] = __builtin_amdgcn_mfma_f32_16x16x32_bf16(a, bh, acc[ct], 0, 0, 0);
      acc[ct] = __builtin_amdgcn_mfma_f32_16x16x32_bf16(a, bl, acc[ct], 0, 0, 0);
    }
  }
  int r0 = rb + (l >> 4) * 4;
  int col = l & 15;
#pragma unroll
  for (int ct = 0; ct < 8; ++ct) {
#pragma unroll
    for (int r = 0; r < 4; ++r) {
      int row = r0 + r;
      if (row < N) {
        float v = acc[ct][r];
        if (RELU) v = fmaxf(v + bs[ct], 0.f);
        C[(size_t)row * 128 + ct * 16 + col] = (unsigned short)bf16_rne(v);
      }
    }
  }
}

// wave-per-node: mean-aggregate Ph[:,0:64] (bf16), add Ph[n,64:]+b2, relu,
// dot Wfc, sigmoid
__global__ __launch_bounds__(256) void k_final(const unsigned short* __restrict__ Ph,
                                               const int* __restrict__ off,
                                               const int* __restrict__ csr,
                                               const float* __restrict__ b2,
                                               const float* __restrict__ Wfc,
                                               const float* __restrict__ bfc,
                                               float* __restrict__ out, int n) {
  int lane = threadIdx.x & 63;
  int node = blockIdx.x * 4 + (threadIdx.x >> 6);
  if (node >= n) return;
  int s = off[node], e = off[node + 1];
  float a0 = 0, a1 = 0, a2 = 0, a3 = 0;
  int i = s;
  for (; i + 4 <= e; i += 4) {
    int s0 = csr[i], s1 = csr[i + 1], s2 = csr[i + 2], s3 = csr[i + 3];
    a0 += bf16s(Ph[(size_t)s0 * 128 + lane]);
    a1 += bf16s(Ph[(size_t)s1 * 128 + lane]);
    a2 += bf16s(Ph[(size_t)s2 * 128 + lane]);
    a3 += bf16s(Ph[(size_t)s3 * 128 + lane]);
  }
  for (; i < e; ++i) a0 += bf16s(Ph[(size_t)csr[i] * 128 + lane]);
  int deg = e - s;
  float inv = 1.0f / (float)(deg > 0 ? deg : 1);
  float h = (a0 + a1 + a2 + a3) * inv + bf16s(Ph[(size_t)node * 128 + 64 + lane]) + b2[lane];
  h = fmaxf(h, 0.f);
  float v = h * Wfc[lane];
#pragma unroll
  for (int o2 = 32; o2 > 0; o2 >>= 1) v += __shfl_xor(v, o2, 64);
  if (lane == 0) out[node] = 1.0f / (1.0f + expf(-(v + bfc[0])));
}

extern "C" void kernel_launch(void* const* d_in, const int* in_sizes, int n_in,
                              void* d_out, int out_size, void* d_ws, size_t ws_size,
                              hipStream_t stream) {
  const float* x   = (const float*)d_in[0];
  const int*   ei  = (const int*)d_in[1];
  const float* W1l = (const float*)d_in[2];
  const float* b1  = (const float*)d_in[3];
  const float* W1r = (const float*)d_in[4];
  const float* W2l = (const float*)d_in[5];
  const float* b2  = (const float*)d_in[6];
  const float* W2r = (const float*)d_in[7];
  const float* Wfc = (const float*)d_in[8];
  const float* bfc = (const float*)d_in[9];
  float* out = (float*)d_out;

  const int N = in_sizes[0] / 128;
  const int E = in_sizes[1] / 2;
  const int* srcp = ei;       // edge_index[0]
  const int* dstp = ei + E;   // edge_index[1]
  const int NB = (N + 15) / 16; // 6250 <= NB_MAX

  // workspace layout (256B aligned regions), ~93 MB total
  char* w = (char*)d_ws;
  auto alloc = [&](size_t bytes) -> void* {
    void* p = (void*)w;
    w += (bytes + 255) & ~(size_t)255;
    return p;
  };
  int*            off   = (int*)alloc((size_t)(N + 1) * 4);
  int*            boff  = (int*)alloc((size_t)(NB + 1) * 4);
  int*            btot  = (int*)alloc((size_t)NB * 4);
  int*            bsum  = (int*)alloc(4096);
  int*            histG = (int*)alloc((size_t)B_PART * NB * 4);
  int*            S2    = (int*)alloc((size_t)B_PART * NB * 4);
  int*            csr   = (int*)alloc((size_t)E * 4);
  unsigned*       xh    = (unsigned*)alloc((size_t)N * 64 * 4);  // bf16 x
  unsigned*       M     = (unsigned*)alloc((size_t)N * 64 * 4);  // bf16 agg; later Ph
  unsigned short* H1b   = (unsigned short*)alloc((size_t)N * 128 * 2);
  unsigned short* p1h   = (unsigned short*)alloc(32768 * 2);
  unsigned short* p1l   = (unsigned short*)alloc(32768 * 2);
  unsigned short* p2h   = (unsigned short*)alloc(16384 * 2);
  unsigned short* p2l   = (unsigned short*)alloc(16384 * 2);
  unsigned* tmp = (unsigned*)H1b;  // lifetimes disjoint: tmp dead before k_mm<8> writes H1b
  unsigned short* Ph = (unsigned short*)M;  // M dead after k_mm<8> reads it

  const int nbB = (NB + 255) / 256; // 25 <= 512 (scan partials capacity)

  k_cvt<<<1024, 256, 0, stream>>>((const float2*)x, xh, N * 64);
  k_wprep<<<192, 256, 0, stream>>>(W1l, W1r, W2l, W2r, p1h, p1l, p2h, p2l);
  k_hist<<<B_PART, 256, 0, stream>>>(dstp, histG, NB, E);
  k_btot<<<nbB, 256, 0, stream>>>(histG, btot, NB);
  k_scan_block<<<nbB, 256, 0, stream>>>(btot, boff, bsum, NB);
  k_scan_partials<<<1, 512, 0, stream>>>(bsum, nbB);
  k_scan_add<<<nbB, 256, 0, stream>>>(boff, bsum, NB, E);
  k_scur<<<nbB, 256, 0, stream>>>(boff, histG, S2, NB);
  k_binA<<<B_PART, 256, 0, stream>>>(srcp, dstp, S2, tmp, NB, E);
  k_binB<<<(NB + 3) / 4, 256, 0, stream>>>(tmp, boff, off, csr, NB, N, E);
  k_agg128<<<(N + 3) / 4, 256, 0, stream>>>(xh, off, csr, M, N);
  k_mm<8, true, true><<<(N + 63) / 64, 256, 0, stream>>>(
      (const unsigned short*)M, (const unsigned short*)xh, p1h, p1l, b1, H1b, N);
  k_mm<4, false, false><<<(N + 63) / 64, 256, 0, stream>>>(
      H1b, nullptr, p2h, p2l, nullptr, Ph, N);
  k_final<<<(N + 3) / 4, 256, 0, stream>>>(Ph, off, csr, b2, Wfc, bfc, out, N);
}

// Round 6
// 528.893 us; speedup vs baseline: 1.5157x; 1.2403x over previous
//
#include <hip/hip_runtime.h>
#include <math.h>

// ---------------------------------------------------------------------------
// GraphSAGE (2x SAGEConv mean + FC + sigmoid) on MI355X.
//
// CSR build = 2-level radix partition, zero per-edge global atomics:
//   round-4 lesson: per-edge global atomics push ~32B each through TCC
//     (196 MB writes for 600 KB of counters).
//   round-5 lesson: 6250 LDS buckets forced 64-block grids (2.75% occupancy)
//     and 32B slices (6x write amp from cross-XCD line sharing).
//   Now: 391 coarse buckets (dst>>8, 256 nodes each) -> 1.6 KB LDS, 512
//   blocks, 16-entry slices but per-block active write set = 25 KB (L2-
//   resident, lines fill before eviction).
//   1) k_hist1: 512 blocks, chunked edge partition, LDS histogram ->
//      histG[512][391] (plain coalesced flush)
//   2) k_btot + k_gscan + k_scur -> goff[], S2[512][391] slice starts
//   3) k_part1: same partition, LDS cursors, scatter packed
//      (dst&255)<<17|src into private slices of tmp
//   4) k_part2: block-per-group (391): LDS count 256 node degrees -> block
//      scan emits off[] for free -> place pass -> exact CSR slot (random 4B
//      writes confined to ~33 KB L2-resident region)
//   5) agg128: mean-aggregate xh (bf16) over neighbors -> M [N,128] bf16
//   6) mm<8,2A,relu>: H1b = relu([M|xh] @ [W1l;W1r] + b1)  bf16 MFMA
//   7) mm<4,1A,->   : Ph  = H1b @ [W2l|W2r]                bf16 MFMA
//      (split-bf16 weights: W = Whi + Wlo, 2 accumulating MFMAs)
//   8) final: mean-aggregate Ph[:,0:64], + Ph[n,64:]+b2, relu, dot Wfc,
//      sigmoid -> out[n]
// Uses mean(h1)@W2l == mean(h1@W2l) to halve layer-2 gather bytes.
// ---------------------------------------------------------------------------

#define P1B 512       // blocks in hist1/part1 (S2 is per-block; must match)
#define CHUNK 1024    // edge chunk size for the block partition
#define NG_MAX 400    // coarse-bucket LDS capacity (N <= 102400)

typedef __attribute__((ext_vector_type(8))) short bf16x8;
typedef __attribute__((ext_vector_type(4))) float f32x4;

__device__ __forceinline__ unsigned bf16_rne(float f) {
  unsigned u = __float_as_uint(f);
  return (u + 0x7FFFu + ((u >> 16) & 1u)) >> 16;
}
__device__ __forceinline__ unsigned pack2(float a, float b) {
  return bf16_rne(a) | (bf16_rne(b) << 16);
}
__device__ __forceinline__ float bf16lo(unsigned u) { return __uint_as_float(u << 16); }
__device__ __forceinline__ float bf16hi(unsigned u) { return __uint_as_float(u & 0xFFFF0000u); }
__device__ __forceinline__ float bf16s(unsigned short v) { return __uint_as_float(((unsigned)v) << 16); }

// x fp32 -> xh bf16 (packed pairs)
__global__ __launch_bounds__(256) void k_cvt(const float2* __restrict__ x,
                                             unsigned* __restrict__ xh, int n2) {
  int stride = gridDim.x * 256;
  for (int i = blockIdx.x * 256 + threadIdx.x; i < n2; i += stride) {
    float2 v = x[i];
    xh[i] = pack2(v.x, v.y);
  }
}

// W (fp32) -> split-bf16 B-fragments in MFMA order:
// p[((kt*8+ct)*64 + lane)*8 + j] = Wcat[kt*32 + (lane>>4)*8 + j][ct*16 + (lane&15)]
__global__ __launch_bounds__(256) void k_wprep(const float* __restrict__ W1l,
                                               const float* __restrict__ W1r,
                                               const float* __restrict__ W2l,
                                               const float* __restrict__ W2r,
                                               unsigned short* __restrict__ p1h,
                                               unsigned short* __restrict__ p1l,
                                               unsigned short* __restrict__ p2h,
                                               unsigned short* __restrict__ p2l) {
  int idx = blockIdx.x * 256 + threadIdx.x;
  if (idx < 32768) {
    int j = idx & 7, l = (idx >> 3) & 63, ct = (idx >> 9) & 7, kt = idx >> 12;
    int k = kt * 32 + (l >> 4) * 8 + j;
    int c = ct * 16 + (l & 15);
    float wv = (k < 128) ? W1l[k * 128 + c] : W1r[(k - 128) * 128 + c];
    unsigned short hi = (unsigned short)bf16_rne(wv);
    float hif = __uint_as_float(((unsigned)hi) << 16);
    unsigned short lo = (unsigned short)bf16_rne(wv - hif);
    p1h[idx] = hi; p1l[idx] = lo;
  } else if (idx < 49152) {
    int i2 = idx - 32768;
    int j = i2 & 7, l = (i2 >> 3) & 63, ct = (i2 >> 9) & 7, kt = i2 >> 12;
    int k = kt * 32 + (l >> 4) * 8 + j;
    int c = ct * 16 + (l & 15);
    float wv = (c < 64) ? W2l[k * 64 + c] : W2r[k * 64 + (c - 64)];
    unsigned short hi = (unsigned short)bf16_rne(wv);
    float hif = __uint_as_float(((unsigned)hi) << 16);
    unsigned short lo = (unsigned short)bf16_rne(wv - hif);
    p2h[i2] = hi; p2l[i2] = lo;
  }
}

// 1) per-block LDS coarse histogram (NG buckets); coalesced flush
__global__ __launch_bounds__(256) void k_hist1(const int* __restrict__ dst,
                                               int* __restrict__ histG,
                                               int NG, int E) {
  __shared__ int h[NG_MAX];
  for (int i = threadIdx.x; i < NG; i += 256) h[i] = 0;
  __syncthreads();
  for (int c = blockIdx.x; c * CHUNK < E; c += gridDim.x) {
    int e0 = c * CHUNK, e1 = min(e0 + CHUNK, E);
    for (int e = e0 + threadIdx.x; e < e1; e += 256)
      atomicAdd(&h[dst[e] >> 8], 1);
  }
  __syncthreads();
  for (int i = threadIdx.x; i < NG; i += 256) histG[blockIdx.x * NG + i] = h[i];
}

// bucket totals (rows coalesced across b)
__global__ __launch_bounds__(256) void k_btot(const int* __restrict__ histG,
                                              int* __restrict__ btot, int NG) {
  int b = blockIdx.x * 256 + threadIdx.x;
  if (b >= NG) return;
  int s = 0;
  for (int k = 0; k < P1B; ++k) s += histG[k * NG + b];
  btot[b] = s;
}

// single-block exclusive scan of NG (<=512) bucket totals -> goff[0..NG]
__global__ void k_gscan(const int* __restrict__ btot, int* __restrict__ goff,
                        int ng, int E) {
  __shared__ int sh[512];
  int t = threadIdx.x;
  int v = (t < ng) ? btot[t] : 0;
  sh[t] = v;
  __syncthreads();
  int x = v;
  for (int d = 1; d < 512; d <<= 1) {
    int y = (t >= d) ? sh[t - d] : 0;
    __syncthreads();
    x += y;
    sh[t] = x;
    __syncthreads();
  }
  if (t < ng) goff[t] = x - v;
  if (t == 0) goff[ng] = E;
}

// per-(block,bucket) slice starts
__global__ __launch_bounds__(256) void k_scur(const int* __restrict__ goff,
                                              const int* __restrict__ histG,
                                              int* __restrict__ S2, int NG) {
  int b = blockIdx.x * 256 + threadIdx.x;
  if (b >= NG) return;
  int run = goff[b];
  for (int k = 0; k < P1B; ++k) {
    S2[k * NG + b] = run;
    run += histG[k * NG + b];
  }
}

// 3) scatter into private per-(block,bucket) slices; LDS cursors only.
// Chunk partition MUST match k_hist1 (same grid, same CHUNK).
__global__ __launch_bounds__(256) void k_part1(const int* __restrict__ src,
                                               const int* __restrict__ dst,
                                               const int* __restrict__ S2,
                                               unsigned* __restrict__ tmp,
                                               int NG, int E) {
  __shared__ int cur[NG_MAX];
  for (int i = threadIdx.x; i < NG; i += 256) cur[i] = S2[blockIdx.x * NG + i];
  __syncthreads();
  for (int c = blockIdx.x; c * CHUNK < E; c += gridDim.x) {
    int e0 = c * CHUNK, e1 = min(e0 + CHUNK, E);
    for (int e = e0 + threadIdx.x; e < e1; e += 256) {
      int d = dst[e];
      int p = atomicAdd(&cur[d >> 8], 1);
      tmp[p] = (unsigned)src[e] | ((unsigned)(d & 255) << 17); // src < 2^17
    }
  }
}

// 4) block-per-group: count 256 node degrees (LDS) -> block scan -> off[];
//    place pass -> exact CSR slot (writes confined to group's region).
__global__ __launch_bounds__(256) void k_part2(const unsigned* __restrict__ tmp,
                                               const int* __restrict__ goff,
                                               int* __restrict__ off,
                                               int* __restrict__ csr,
                                               int NG, int N, int E) {
  __shared__ int sh[256];
  __shared__ int cur[256];
  int g = blockIdx.x, t = threadIdx.x;
  int s = goff[g], e = goff[g + 1];
  int n0 = g * 256;
  sh[t] = 0;
  __syncthreads();
  for (int i = s + t; i < e; i += 256) atomicAdd(&sh[tmp[i] >> 17], 1);
  __syncthreads();
  int v = sh[t];
  __syncthreads();
  sh[t] = v;
  __syncthreads();
  int x = v;
  for (int d = 1; d < 256; d <<= 1) {
    int y = (t >= d) ? sh[t - d] : 0;
    __syncthreads();
    x += y;
    sh[t] = x;
    __syncthreads();
  }
  int base = s + x - v;  // exclusive prefix within group
  cur[t] = base;
  if (n0 + t < N) off[n0 + t] = base;
  if (g == NG - 1 && t == 0) off[N] = E;
  __syncthreads();
  for (int i = s + t; i < e; i += 256) {
    unsigned u = tmp[i];
    int pos = atomicAdd(&cur[u >> 17], 1);
    csr[pos] = (int)(u & 0x1FFFFu);
  }
}

// wave-per-node mean aggregation of bf16 128-dim rows -> M (bf16)
__global__ __launch_bounds__(256) void k_agg128(const unsigned* __restrict__ xh,
                                                const int* __restrict__ off,
                                                const int* __restrict__ csr,
                                                unsigned* __restrict__ M, int n) {
  int lane = threadIdx.x & 63;
  int node = blockIdx.x * 4 + (threadIdx.x >> 6);
  if (node >= n) return;
  int s = off[node], e = off[node + 1];
  float ax0 = 0, ay0 = 0, ax1 = 0, ay1 = 0, ax2 = 0, ay2 = 0, ax3 = 0, ay3 = 0;
  int i = s;
  for (; i + 4 <= e; i += 4) {
    int s0 = csr[i], s1 = csr[i + 1], s2 = csr[i + 2], s3 = csr[i + 3];
    unsigned u0 = xh[(size_t)s0 * 64 + lane];
    unsigned u1 = xh[(size_t)s1 * 64 + lane];
    unsigned u2 = xh[(size_t)s2 * 64 + lane];
    unsigned u3 = xh[(size_t)s3 * 64 + lane];
    ax0 += bf16lo(u0); ay0 += bf16hi(u0);
    ax1 += bf16lo(u1); ay1 += bf16hi(u1);
    ax2 += bf16lo(u2); ay2 += bf16hi(u2);
    ax3 += bf16lo(u3); ay3 += bf16hi(u3);
  }
  for (; i < e; ++i) {
    unsigned u0 = xh[(size_t)csr[i] * 64 + lane];
    ax0 += bf16lo(u0); ay0 += bf16hi(u0);
  }
  int deg = e - s;
  float inv = 1.0f / (float)(deg > 0 ? deg : 1);
  float rx = (ax0 + ax1 + ax2 + ax3) * inv;
  float ry = (ay0 + ay1 + ay2 + ay3) * inv;
  M[(size_t)node * 64 + lane] = pack2(rx, ry);
}

// MFMA GEMM: C(bf16)[N,128] = act(A @ W + bias); 1 wave = 16 rows x 128 cols.
// Layouts (CDNA4 16x16x32): A row=l&15, k=(l>>4)*8+j; B col=l&15, same k;
// D col=l&15, row=(l>>4)*4+reg  [m89-verified].
template <int KSTEPS, bool TWOA, bool RELU>
__global__ __launch_bounds__(256) void k_mm(const unsigned short* __restrict__ A0,
                                            const unsigned short* __restrict__ A1,
                                            const unsigned short* __restrict__ Bh,
                                            const unsigned short* __restrict__ Bl,
                                            const float* __restrict__ bias,
                                            unsigned short* __restrict__ C, int N) {
  int l = threadIdx.x & 63, wv = threadIdx.x >> 6;
  int rb = blockIdx.x * 64 + wv * 16;
  int arow = rb + (l & 15);
  if (arow > N - 1) arow = N - 1;                     // clamp: loads stay in-bounds
  const size_t aoff = (size_t)arow * 128 + ((l >> 4) * 8);
  f32x4 acc[8] = {};
  float bs[8];
  if (RELU) {
#pragma unroll
    for (int ct = 0; ct < 8; ++ct) bs[ct] = bias[ct * 16 + (l & 15)];
  }
#pragma unroll 2
  for (int kt = 0; kt < KSTEPS; ++kt) {
    const unsigned short* At = TWOA ? (kt < KSTEPS / 2 ? A0 : A1) : A0;
    int ko = TWOA ? (kt < KSTEPS / 2 ? kt : kt - KSTEPS / 2) : kt;
    bf16x8 a = *(const bf16x8*)(At + aoff + (size_t)ko * 32);
#pragma unroll
    for (int ct = 0; ct < 8; ++ct) {
      bf16x8 bh = *(const bf16x8*)(Bh + (((size_t)(kt * 8 + ct) * 64 + l) * 8));
      bf16x8 bl = *(const bf16x8*)(Bl + (((size_t)(kt * 8 + ct) * 64 + l) * 8));
      acc[ct] = __builtin_amdgcn_mfma_f32_16x16x32_bf16(a, bh, acc[ct], 0, 0, 0);
      acc[ct] = __builtin_amdgcn_mfma_f32_16x16x32_bf16(a, bl, acc[ct], 0, 0, 0);
    }
  }
  int r0 = rb + (l >> 4) * 4;
  int col = l & 15;
#pragma unroll
  for (int ct = 0; ct < 8; ++ct) {
#pragma unroll
    for (int r = 0; r < 4; ++r) {
      int row = r0 + r;
      if (row < N) {
        float v = acc[ct][r];
        if (RELU) v = fmaxf(v + bs[ct], 0.f);
        C[(size_t)row * 128 + ct * 16 + col] = (unsigned short)bf16_rne(v);
      }
    }
  }
}

// wave-per-node: mean-aggregate Ph[:,0:64] (bf16), add Ph[n,64:]+b2, relu,
// dot Wfc, sigmoid
__global__ __launch_bounds__(256) void k_final(const unsigned short* __restrict__ Ph,
                                               const int* __restrict__ off,
                                               const int* __restrict__ csr,
                                               const float* __restrict__ b2,
                                               const float* __restrict__ Wfc,
                                               const float* __restrict__ bfc,
                                               float* __restrict__ out, int n) {
  int lane = threadIdx.x & 63;
  int node = blockIdx.x * 4 + (threadIdx.x >> 6);
  if (node >= n) return;
  int s = off[node], e = off[node + 1];
  float a0 = 0, a1 = 0, a2 = 0, a3 = 0;
  int i = s;
  for (; i + 4 <= e; i += 4) {
    int s0 = csr[i], s1 = csr[i + 1], s2 = csr[i + 2], s3 = csr[i + 3];
    a0 += bf16s(Ph[(size_t)s0 * 128 + lane]);
    a1 += bf16s(Ph[(size_t)s1 * 128 + lane]);
    a2 += bf16s(Ph[(size_t)s2 * 128 + lane]);
    a3 += bf16s(Ph[(size_t)s3 * 128 + lane]);
  }
  for (; i < e; ++i) a0 += bf16s(Ph[(size_t)csr[i] * 128 + lane]);
  int deg = e - s;
  float inv = 1.0f / (float)(deg > 0 ? deg : 1);
  float h = (a0 + a1 + a2 + a3) * inv + bf16s(Ph[(size_t)node * 128 + 64 + lane]) + b2[lane];
  h = fmaxf(h, 0.f);
  float v = h * Wfc[lane];
#pragma unroll
  for (int o2 = 32; o2 > 0; o2 >>= 1) v += __shfl_xor(v, o2, 64);
  if (lane == 0) out[node] = 1.0f / (1.0f + expf(-(v + bfc[0])));
}

extern "C" void kernel_launch(void* const* d_in, const int* in_sizes, int n_in,
                              void* d_out, int out_size, void* d_ws, size_t ws_size,
                              hipStream_t stream) {
  const float* x   = (const float*)d_in[0];
  const int*   ei  = (const int*)d_in[1];
  const float* W1l = (const float*)d_in[2];
  const float* b1  = (const float*)d_in[3];
  const float* W1r = (const float*)d_in[4];
  const float* W2l = (const float*)d_in[5];
  const float* b2  = (const float*)d_in[6];
  const float* W2r = (const float*)d_in[7];
  const float* Wfc = (const float*)d_in[8];
  const float* bfc = (const float*)d_in[9];
  float* out = (float*)d_out;

  const int N = in_sizes[0] / 128;
  const int E = in_sizes[1] / 2;
  const int* srcp = ei;       // edge_index[0]
  const int* dstp = ei + E;   // edge_index[1]
  const int NG = (N + 255) / 256; // 391 <= NG_MAX, <= 512 (gscan capacity)

  // workspace layout (256B aligned regions), ~95 MB total
  char* w = (char*)d_ws;
  auto alloc = [&](size_t bytes) -> void* {
    void* p = (void*)w;
    w += (bytes + 255) & ~(size_t)255;
    return p;
  };
  int*            off   = (int*)alloc((size_t)(N + 1) * 4);
  int*            goff  = (int*)alloc((size_t)(NG + 1) * 4);
  int*            btot  = (int*)alloc((size_t)NG * 4);
  int*            histG = (int*)alloc((size_t)P1B * NG * 4);
  int*            S2    = (int*)alloc((size_t)P1B * NG * 4);
  int*            csr   = (int*)alloc((size_t)E * 4);
  unsigned*       xh    = (unsigned*)alloc((size_t)N * 64 * 4);  // bf16 x
  unsigned*       M     = (unsigned*)alloc((size_t)N * 64 * 4);  // bf16 agg; later Ph
  unsigned short* H1b   = (unsigned short*)alloc((size_t)N * 128 * 2);
  unsigned short* p1h   = (unsigned short*)alloc(32768 * 2);
  unsigned short* p1l   = (unsigned short*)alloc(32768 * 2);
  unsigned short* p2h   = (unsigned short*)alloc(16384 * 2);
  unsigned short* p2l   = (unsigned short*)alloc(16384 * 2);
  unsigned* tmp = (unsigned*)H1b;  // lifetimes disjoint: tmp dead before k_mm<8> writes H1b
  unsigned short* Ph = (unsigned short*)M;  // M dead after k_mm<8> reads it

  const int ngB = (NG + 255) / 256; // 2

  k_cvt<<<1024, 256, 0, stream>>>((const float2*)x, xh, N * 64);
  k_wprep<<<192, 256, 0, stream>>>(W1l, W1r, W2l, W2r, p1h, p1l, p2h, p2l);
  k_hist1<<<P1B, 256, 0, stream>>>(dstp, histG, NG, E);
  k_btot<<<ngB, 256, 0, stream>>>(histG, btot, NG);
  k_gscan<<<1, 512, 0, stream>>>(btot, goff, NG, E);
  k_scur<<<ngB, 256, 0, stream>>>(goff, histG, S2, NG);
  k_part1<<<P1B, 256, 0, stream>>>(srcp, dstp, S2, tmp, NG, E);
  k_part2<<<NG, 256, 0, stream>>>(tmp, goff, off, csr, NG, N, E);
  k_agg128<<<(N + 3) / 4, 256, 0, stream>>>(xh, off, csr, M, N);
  k_mm<8, true, true><<<(N + 63) / 64, 256, 0, stream>>>(
      (const unsigned short*)M, (const unsigned short*)xh, p1h, p1l, b1, H1b, N);
  k_mm<4, false, false><<<(N + 63) / 64, 256, 0, stream>>>(
      H1b, nullptr, p2h, p2l, nullptr, Ph, N);
  k_final<<<(N + 3) / 4, 256, 0, stream>>>(Ph, off, csr, b2, Wfc, bfc, out, N);
}

// Round 8
// 512.806 us; speedup vs baseline: 1.5633x; 1.0314x over previous
//
#include <hip/hip_runtime.h>
#include <math.h>

// ---------------------------------------------------------------------------
// GraphSAGE (2x SAGEConv mean + FC + sigmoid) on MI355X.
//
// CSR build = 2-level radix partition (391 coarse groups of 256 nodes), zero
// per-edge global atomics (round-4/5 lessons: global atomics write ~32B each
// through TCC; tiny-slice scatters cause cross-XCD line churn).
// Gather precision plan: values that feed the NEIGHBOR MEAN are stored
// fp8-e4m3 (error /sqrt(deg) in the mean); self/lin_r paths and all GEMM
// operands stay bf16 (split-bf16 weights ~ fp32). HW v_cvt_pk_f32_fp8
// decodes 2 elems/op (cheaper than bf16 unpack).
//   1) k_cvt: x -> xh bf16 [N,128] + xq fp8 [N,128]; k_wprep: W -> B-frags
//   2) k_hist1 (512 blk, LDS hist) -> histG; k_btot/k_gscan/k_scur -> S2
//   3) k_part1: scatter packed (dst&255)<<17|src into private slices
//   4) k_part2: block-per-group count+scan (emits off[]) + place -> csr
//   5) k_agg128: mean-gather xq (128 B/row) -> M [N,128] bf16
//   6) mm<8,2A,relu>: H1b = relu([M|xh] @ [W1l;W1r] + b1)  bf16 MFMA
//   7) mm<4,1A,->   : P = H1b @ [W2l|W2r]; cols 0-63 -> Pg fp8 (gather
//      table, 6.4 MB ~ L2-resident), cols 64-127 -> Ps bf16 (self term)
//   8) k_final: mean-gather Pg (64 B/row) + Ps[n]+b2, relu, dot Wfc, sigmoid
// Uses mean(h1)@W2l == mean(h1@W2l) to shrink layer-2 gather to 64 cols.
// ---------------------------------------------------------------------------

#define P1B 512       // blocks in hist1/part1 (S2 is per-block; must match)
#define CHUNK 1024    // edge chunk size for the block partition
#define NG_MAX 400    // coarse-bucket LDS capacity (N <= 102400)

typedef __attribute__((ext_vector_type(8))) short bf16x8;
typedef __attribute__((ext_vector_type(4))) float f32x4;
typedef __attribute__((ext_vector_type(2))) float f32x2;

__device__ __forceinline__ unsigned bf16_rne(float f) {
  unsigned u = __float_as_uint(f);
  return (u + 0x7FFFu + ((u >> 16) & 1u)) >> 16;
}
__device__ __forceinline__ unsigned pack2(float a, float b) {
  return bf16_rne(a) | (bf16_rne(b) << 16);
}
__device__ __forceinline__ float bf16lo(unsigned u) { return __uint_as_float(u << 16); }
__device__ __forceinline__ float bf16hi(unsigned u) { return __uint_as_float(u & 0xFFFF0000u); }
__device__ __forceinline__ float bf16s(unsigned short v) { return __uint_as_float(((unsigned)v) << 16); }

// x fp32 -> xh bf16 (packed pairs) + xq fp8 e4m3 (packed quads)
__global__ __launch_bounds__(256) void k_cvt(const float4* __restrict__ x,
                                             uint2* __restrict__ xh,
                                             unsigned* __restrict__ xq, int n4) {
  int stride = gridDim.x * 256;
  for (int i = blockIdx.x * 256 + threadIdx.x; i < n4; i += stride) {
    float4 v = x[i];
    xh[i] = make_uint2(pack2(v.x, v.y), pack2(v.z, v.w));
    unsigned q = __builtin_amdgcn_cvt_pk_fp8_f32(v.x, v.y, 0u, false);
    q = __builtin_amdgcn_cvt_pk_fp8_f32(v.z, v.w, q, true);
    xq[i] = q;
  }
}

// W (fp32) -> split-bf16 B-fragments in MFMA order:
// p[((kt*8+ct)*64 + lane)*8 + j] = Wcat[kt*32 + (lane>>4)*8 + j][ct*16 + (lane&15)]
__global__ __launch_bounds__(256) void k_wprep(const float* __restrict__ W1l,
                                               const float* __restrict__ W1r,
                                               const float* __restrict__ W2l,
                                               const float* __restrict__ W2r,
                                               unsigned short* __restrict__ p1h,
                                               unsigned short* __restrict__ p1l,
                                               unsigned short* __restrict__ p2h,
                                               unsigned short* __restrict__ p2l) {
  int idx = blockIdx.x * 256 + threadIdx.x;
  if (idx < 32768) {
    int j = idx & 7, l = (idx >> 3) & 63, ct = (idx >> 9) & 7, kt = idx >> 12;
    int k = kt * 32 + (l >> 4) * 8 + j;
    int c = ct * 16 + (l & 15);
    float wv = (k < 128) ? W1l[k * 128 + c] : W1r[(k - 128) * 128 + c];
    unsigned short hi = (unsigned short)bf16_rne(wv);
    float hif = __uint_as_float(((unsigned)hi) << 16);
    unsigned short lo = (unsigned short)bf16_rne(wv - hif);
    p1h[idx] = hi; p1l[idx] = lo;
  } else if (idx < 49152) {
    int i2 = idx - 32768;
    int j = i2 & 7, l = (i2 >> 3) & 63, ct = (i2 >> 9) & 7, kt = i2 >> 12;
    int k = kt * 32 + (l >> 4) * 8 + j;
    int c = ct * 16 + (l & 15);
    float wv = (c < 64) ? W2l[k * 64 + c] : W2r[k * 64 + (c - 64)];
    unsigned short hi = (unsigned short)bf16_rne(wv);
    float hif = __uint_as_float(((unsigned)hi) << 16);
    unsigned short lo = (unsigned short)bf16_rne(wv - hif);
    p2h[i2] = hi; p2l[i2] = lo;
  }
}

// 1) per-block LDS coarse histogram (NG buckets); coalesced flush
__global__ __launch_bounds__(256) void k_hist1(const int* __restrict__ dst,
                                               int* __restrict__ histG,
                                               int NG, int E) {
  __shared__ int h[NG_MAX];
  for (int i = threadIdx.x; i < NG; i += 256) h[i] = 0;
  __syncthreads();
  for (int c = blockIdx.x; c * CHUNK < E; c += gridDim.x) {
    int e0 = c * CHUNK, e1 = min(e0 + CHUNK, E);
    for (int e = e0 + threadIdx.x; e < e1; e += 256)
      atomicAdd(&h[dst[e] >> 8], 1);
  }
  __syncthreads();
  for (int i = threadIdx.x; i < NG; i += 256) histG[blockIdx.x * NG + i] = h[i];
}

// bucket totals (rows coalesced across b)
__global__ __launch_bounds__(256) void k_btot(const int* __restrict__ histG,
                                              int* __restrict__ btot, int NG) {
  int b = blockIdx.x * 256 + threadIdx.x;
  if (b >= NG) return;
  int s = 0;
  for (int k = 0; k < P1B; ++k) s += histG[k * NG + b];
  btot[b] = s;
}

// single-block exclusive scan of NG (<=512) bucket totals -> goff[0..NG]
__global__ void k_gscan(const int* __restrict__ btot, int* __restrict__ goff,
                        int ng, int E) {
  __shared__ int sh[512];
  int t = threadIdx.x;
  int v = (t < ng) ? btot[t] : 0;
  sh[t] = v;
  __syncthreads();
  int x = v;
  for (int d = 1; d < 512; d <<= 1) {
    int y = (t >= d) ? sh[t - d] : 0;
    __syncthreads();
    x += y;
    sh[t] = x;
    __syncthreads();
  }
  if (t < ng) goff[t] = x - v;
  if (t == 0) goff[ng] = E;
}

// per-(block,bucket) slice starts
__global__ __launch_bounds__(256) void k_scur(const int* __restrict__ goff,
                                              const int* __restrict__ histG,
                                              int* __restrict__ S2, int NG) {
  int b = blockIdx.x * 256 + threadIdx.x;
  if (b >= NG) return;
  int run = goff[b];
  for (int k = 0; k < P1B; ++k) {
    S2[k * NG + b] = run;
    run += histG[k * NG + b];
  }
}

// 3) scatter into private per-(block,bucket) slices; LDS cursors only.
// Chunk partition MUST match k_hist1 (same grid, same CHUNK).
__global__ __launch_bounds__(256) void k_part1(const int* __restrict__ src,
                                               const int* __restrict__ dst,
                                               const int* __restrict__ S2,
                                               unsigned* __restrict__ tmp,
                                               int NG, int E) {
  __shared__ int cur[NG_MAX];
  for (int i = threadIdx.x; i < NG; i += 256) cur[i] = S2[blockIdx.x * NG + i];
  __syncthreads();
  for (int c = blockIdx.x; c * CHUNK < E; c += gridDim.x) {
    int e0 = c * CHUNK, e1 = min(e0 + CHUNK, E);
    for (int e = e0 + threadIdx.x; e < e1; e += 256) {
      int d = dst[e];
      int p = atomicAdd(&cur[d >> 8], 1);
      tmp[p] = (unsigned)src[e] | ((unsigned)(d & 255) << 17); // src < 2^17
    }
  }
}

// 4) block-per-group: count 256 node degrees (LDS) -> block scan -> off[];
//    place pass -> exact CSR slot (writes confined to group's region).
__global__ __launch_bounds__(256) void k_part2(const unsigned* __restrict__ tmp,
                                               const int* __restrict__ goff,
                                               int* __restrict__ off,
                                               int* __restrict__ csr,
                                               int NG, int N, int E) {
  __shared__ int sh[256];
  __shared__ int cur[256];
  int g = blockIdx.x, t = threadIdx.x;
  int s = goff[g], e = goff[g + 1];
  int n0 = g * 256;
  sh[t] = 0;
  __syncthreads();
  for (int i = s + t; i < e; i += 256) atomicAdd(&sh[tmp[i] >> 17], 1);
  __syncthreads();
  int v = sh[t];
  __syncthreads();
  sh[t] = v;
  __syncthreads();
  int x = v;
  for (int d = 1; d < 256; d <<= 1) {
    int y = (t >= d) ? sh[t - d] : 0;
    __syncthreads();
    x += y;
    sh[t] = x;
    __syncthreads();
  }
  int base = s + x - v;  // exclusive prefix within group
  cur[t] = base;
  if (n0 + t < N) off[n0 + t] = base;
  if (g == NG - 1 && t == 0) off[N] = E;
  __syncthreads();
  for (int i = s + t; i < e; i += 256) {
    unsigned u = tmp[i];
    int pos = atomicAdd(&cur[u >> 17], 1);
    csr[pos] = (int)(u & 0x1FFFFu);
  }
}

// wave-per-node mean aggregation of fp8 128-dim rows -> M (bf16)
// lane handles 2 cols via ushort load + v_cvt_pk_f32_fp8 (2 f32/op)
__global__ __launch_bounds__(256) void k_agg128(const unsigned short* __restrict__ xq,
                                                const int* __restrict__ off,
                                                const int* __restrict__ csr,
                                                unsigned* __restrict__ M, int n) {
  int lane = threadIdx.x & 63;
  int node = blockIdx.x * 4 + (threadIdx.x >> 6);
  if (node >= n) return;
  int s = off[node], e = off[node + 1];
  f32x2 a0 = {0.f, 0.f}, a1 = {0.f, 0.f}, a2 = {0.f, 0.f}, a3 = {0.f, 0.f};
  int i = s;
  for (; i + 4 <= e; i += 4) {
    int s0 = csr[i], s1 = csr[i + 1], s2 = csr[i + 2], s3 = csr[i + 3];
    unsigned u0 = xq[(size_t)s0 * 64 + lane];
    unsigned u1 = xq[(size_t)s1 * 64 + lane];
    unsigned u2 = xq[(size_t)s2 * 64 + lane];
    unsigned u3 = xq[(size_t)s3 * 64 + lane];
    a0 += __builtin_amdgcn_cvt_pk_f32_fp8(u0, false);
    a1 += __builtin_amdgcn_cvt_pk_f32_fp8(u1, false);
    a2 += __builtin_amdgcn_cvt_pk_f32_fp8(u2, false);
    a3 += __builtin_amdgcn_cvt_pk_f32_fp8(u3, false);
  }
  for (; i < e; ++i) {
    unsigned u0 = xq[(size_t)csr[i] * 64 + lane];
    a0 += __builtin_amdgcn_cvt_pk_f32_fp8(u0, false);
  }
  int deg = e - s;
  float inv = 1.0f / (float)(deg > 0 ? deg : 1);
  f32x2 r = (a0 + a1) + (a2 + a3);
  M[(size_t)node * 64 + lane] = pack2(r[0] * inv, r[1] * inv);
}

// MFMA GEMM: 1 wave = 16 rows x 128 cols; block = 4 waves = 64 rows.
// RELU=true : C = bf16 [N,128] = relu(A@W + bias)
// RELU=false: cols 0-63 -> Cg fp8 [N,64] (gather table), cols 64-127 ->
//             Cs bf16 [N,64] (self term, full precision)
// Layouts (CDNA4 16x16x32): A row=l&15, k=(l>>4)*8+j; B col=l&15, same k;
// D col=l&15, row=(l>>4)*4+reg  [m89-verified].
template <int KSTEPS, bool TWOA, bool RELU>
__global__ __launch_bounds__(256) void k_mm(const unsigned short* __restrict__ A0,
                                            const unsigned short* __restrict__ A1,
                                            const unsigned short* __restrict__ Bh,
                                            const unsigned short* __restrict__ Bl,
                                            const float* __restrict__ bias,
                                            unsigned short* __restrict__ C,
                                            unsigned char* __restrict__ Cg,
                                            unsigned short* __restrict__ Cs, int N) {
  int l = threadIdx.x & 63, wv = threadIdx.x >> 6;
  int rb = blockIdx.x * 64 + wv * 16;
  int arow = rb + (l & 15);
  if (arow > N - 1) arow = N - 1;                     // clamp: loads stay in-bounds
  const size_t aoff = (size_t)arow * 128 + ((l >> 4) * 8);
  f32x4 acc[8] = {};
  float bs[8];
  if (RELU) {
#pragma unroll
    for (int ct = 0; ct < 8; ++ct) bs[ct] = bias[ct * 16 + (l & 15)];
  }
#pragma unroll 2
  for (int kt = 0; kt < KSTEPS; ++kt) {
    const unsigned short* At = TWOA ? (kt < KSTEPS / 2 ? A0 : A1) : A0;
    int ko = TWOA ? (kt < KSTEPS / 2 ? kt : kt - KSTEPS / 2) : kt;
    bf16x8 a = *(const bf16x8*)(At + aoff + (size_t)ko * 32);
#pragma unroll
    for (int ct = 0; ct < 8; ++ct) {
      bf16x8 bh = *(const bf16x8*)(Bh + (((size_t)(kt * 8 + ct) * 64 + l) * 8));
      bf16x8 bl = *(const bf16x8*)(Bl + (((size_t)(kt * 8 + ct) * 64 + l) * 8));
      acc[ct] = __builtin_amdgcn_mfma_f32_16x16x32_bf16(a, bh, acc[ct], 0, 0, 0);
      acc[ct] = __builtin_amdgcn_mfma_f32_16x16x32_bf16(a, bl, acc[ct], 0, 0, 0);
    }
  }
  int r0 = rb + (l >> 4) * 4;
  int col = l & 15;
#pragma unroll
  for (int ct = 0; ct < 8; ++ct) {
#pragma unroll
    for (int r = 0; r < 4; ++r) {
      int row = r0 + r;
      if (row < N) {
        float v = acc[ct][r];
        if (RELU) {
          v = fmaxf(v + bs[ct], 0.f);
          C[(size_t)row * 128 + ct * 16 + col] = (unsigned short)bf16_rne(v);
        } else {
          if (ct < 4) {
            unsigned q = __builtin_amdgcn_cvt_pk_fp8_f32(v, v, 0u, false);
            Cg[(size_t)row * 64 + ct * 16 + col] = (unsigned char)(q & 0xFF);
          } else {
            Cs[(size_t)row * 64 + (ct - 4) * 16 + col] = (unsigned short)bf16_rne(v);
          }
        }
      }
    }
  }
}

// wave-per-node: mean-gather Pg fp8 (64 B/row), add Ps[n]+b2, relu, dot Wfc,
// sigmoid
__global__ __launch_bounds__(256) void k_final(const unsigned char* __restrict__ Pg,
                                               const unsigned short* __restrict__ Ps,
                                               const int* __restrict__ off,
                                               const int* __restrict__ csr,
                                               const float* __restrict__ b2,
                                               const float* __restrict__ Wfc,
                                               const float* __restrict__ bfc,
                                               float* __restrict__ out, int n) {
  int lane = threadIdx.x & 63;
  int node = blockIdx.x * 4 + (threadIdx.x >> 6);
  if (node >= n) return;
  int s = off[node], e = off[node + 1];
  float a0 = 0, a1 = 0, a2 = 0, a3 = 0;
  int i = s;
  for (; i + 4 <= e; i += 4) {
    int s0 = csr[i], s1 = csr[i + 1], s2 = csr[i + 2], s3 = csr[i + 3];
    f32x2 v0 = __builtin_amdgcn_cvt_pk_f32_fp8((unsigned)Pg[(size_t)s0 * 64 + lane], false);
    f32x2 v1 = __builtin_amdgcn_cvt_pk_f32_fp8((unsigned)Pg[(size_t)s1 * 64 + lane], false);
    f32x2 v2 = __builtin_amdgcn_cvt_pk_f32_fp8((unsigned)Pg[(size_t)s2 * 64 + lane], false);
    f32x2 v3 = __builtin_amdgcn_cvt_pk_f32_fp8((unsigned)Pg[(size_t)s3 * 64 + lane], false);
    a0 += v0[0]; a1 += v1[0]; a2 += v2[0]; a3 += v3[0];
  }
  for (; i < e; ++i) {
    f32x2 v0 = __builtin_amdgcn_cvt_pk_f32_fp8((unsigned)Pg[(size_t)csr[i] * 64 + lane], false);
    a0 += v0[0];
  }
  int deg = e - s;
  float inv = 1.0f / (float)(deg > 0 ? deg : 1);
  float h = (a0 + a1 + a2 + a3) * inv + bf16s(Ps[(size_t)node * 64 + lane]) + b2[lane];
  h = fmaxf(h, 0.f);
  float v = h * Wfc[lane];
#pragma unroll
  for (int o2 = 32; o2 > 0; o2 >>= 1) v += __shfl_xor(v, o2, 64);
  if (lane == 0) out[node] = 1.0f / (1.0f + expf(-(v + bfc[0])));
}

extern "C" void kernel_launch(void* const* d_in, const int* in_sizes, int n_in,
                              void* d_out, int out_size, void* d_ws, size_t ws_size,
                              hipStream_t stream) {
  const float* x   = (const float*)d_in[0];
  const int*   ei  = (const int*)d_in[1];
  const float* W1l = (const float*)d_in[2];
  const float* b1  = (const float*)d_in[3];
  const float* W1r = (const float*)d_in[4];
  const float* W2l = (const float*)d_in[5];
  const float* b2  = (const float*)d_in[6];
  const float* W2r = (const float*)d_in[7];
  const float* Wfc = (const float*)d_in[8];
  const float* bfc = (const float*)d_in[9];
  float* out = (float*)d_out;

  const int N = in_sizes[0] / 128;
  const int E = in_sizes[1] / 2;
  const int* srcp = ei;       // edge_index[0]
  const int* dstp = ei + E;   // edge_index[1]
  const int NG = (N + 255) / 256; // 391 <= NG_MAX, <= 512 (gscan capacity)

  // workspace layout (256B aligned regions), ~108 MB total
  char* w = (char*)d_ws;
  auto alloc = [&](size_t bytes) -> void* {
    void* p = (void*)w;
    w += (bytes + 255) & ~(size_t)255;
    return p;
  };
  int*            off   = (int*)alloc((size_t)(N + 1) * 4);
  int*            goff  = (int*)alloc((size_t)(NG + 1) * 4);
  int*            btot  = (int*)alloc((size_t)NG * 4);
  int*            histG = (int*)alloc((size_t)P1B * NG * 4);
  int*            S2    = (int*)alloc((size_t)P1B * NG * 4);
  int*            csr   = (int*)alloc((size_t)E * 4);
  unsigned*       xh    = (unsigned*)alloc((size_t)N * 64 * 4);  // bf16 x (lin_r path)
  unsigned*       xq    = (unsigned*)alloc((size_t)N * 32 * 4);  // fp8 x (mean path)
  unsigned*       M     = (unsigned*)alloc((size_t)N * 64 * 4);  // bf16 agg; later Pg+Ps
  unsigned short* H1b   = (unsigned short*)alloc((size_t)N * 128 * 2);
  unsigned short* p1h   = (unsigned short*)alloc(32768 * 2);
  unsigned short* p1l   = (unsigned short*)alloc(32768 * 2);
  unsigned short* p2h   = (unsigned short*)alloc(16384 * 2);
  unsigned short* p2l   = (unsigned short*)alloc(16384 * 2);
  unsigned* tmp = (unsigned*)H1b;  // lifetimes disjoint: tmp dead before k_mm<8> writes H1b
  // M region (25.6 MB) is dead after k_mm<8> reads it; reuse for Pg (6.4 MB) + Ps (12.8 MB)
  unsigned char*  Pg = (unsigned char*)M;
  unsigned short* Ps = (unsigned short*)((char*)M + (size_t)N * 64);

  const int ngB = (NG + 255) / 256; // 2

  k_cvt<<<1024, 256, 0, stream>>>((const float4*)x, (uint2*)xh, xq, N * 32);
  k_wprep<<<192, 256, 0, stream>>>(W1l, W1r, W2l, W2r, p1h, p1l, p2h, p2l);
  k_hist1<<<P1B, 256, 0, stream>>>(dstp, histG, NG, E);
  k_btot<<<ngB, 256, 0, stream>>>(histG, btot, NG);
  k_gscan<<<1, 512, 0, stream>>>(btot, goff, NG, E);
  k_scur<<<ngB, 256, 0, stream>>>(goff, histG, S2, NG);
  k_part1<<<P1B, 256, 0, stream>>>(srcp, dstp, S2, tmp, NG, E);
  k_part2<<<NG, 256, 0, stream>>>(tmp, goff, off, csr, NG, N, E);
  k_agg128<<<(N + 3) / 4, 256, 0, stream>>>((const unsigned short*)xq, off, csr, M, N);
  k_mm<8, true, true><<<(N + 63) / 64, 256, 0, stream>>>(
      (const unsigned short*)M, (const unsigned short*)xh, p1h, p1l, b1, H1b,
      nullptr, nullptr, N);
  k_mm<4, false, false><<<(N + 63) / 64, 256, 0, stream>>>(
      H1b, nullptr, p2h, p2l, nullptr, nullptr, Pg, Ps, N);
  k_final<<<(N + 3) / 4, 256, 0, stream>>>(Pg, Ps, off, csr, b2, Wfc, bfc, out, N);
}

// Round 9
// 499.121 us; speedup vs baseline: 1.6061x; 1.0274x over previous
//
#include <hip/hip_runtime.h>
#include <math.h>

// ---------------------------------------------------------------------------
// GraphSAGE (2x SAGEConv mean + FC + sigmoid) on MI355X.
//
// CSR build = 2-level radix partition (391 coarse groups of 256 nodes), zero
// per-edge global atomics (round-4/5 lessons: global atomics write ~32B each
// through TCC; tiny-slice scatters cause cross-XCD line churn).
// Gather precision: values feeding the NEIGHBOR MEAN are fp8-e4m3 (error
// /sqrt(deg) in the mean); self/lin_r paths + GEMM operands stay bf16
// (split-bf16 weights ~ fp32).
// Round-9: gathers are instruction-bound (k_final: 21 wave-inst/edge, VALU
// 54%) -> process 2 edges per wave-iteration (lane halves), wider per-lane
// loads (ushort/uint + one cvt_pk per 2 cols), 32-bit address arithmetic.
//   1) k_cvt: x -> xh bf16 [N,128] + xq fp8 [N,128]; k_wprep: W -> B-frags
//   2) k_hist1 (512 blk, LDS hist) -> histG; k_btot/k_gscan/k_scur -> S2
//   3) k_part1: scatter packed (dst&255)<<17|src into private slices
//   4) k_part2: block-per-group count+scan (emits off[]) + place -> csr
//   5) k_agg128: mean-gather xq (128 B/row, 2 edges/iter) -> M [N,128] bf16
//   6) mm<8,2A,relu>: H1b = relu([M|xh] @ [W1l;W1r] + b1)  bf16 MFMA
//   7) mm<4,1A,->   : P = H1b @ [W2l|W2r]; cols 0-63 -> Pg fp8, 64-127 ->
//      Ps bf16 (self term)
//   8) k_final: mean-gather Pg (64 B/row, 2 edges/iter) + Ps[n]+b2, relu,
//      dot Wfc, sigmoid
// Uses mean(h1)@W2l == mean(h1@W2l) to shrink layer-2 gather to 64 cols.
// ---------------------------------------------------------------------------

#define P1B 512       // blocks in hist1/part1 (S2 is per-block; must match)
#define CHUNK 1024    // edge chunk size for the block partition
#define NG_MAX 400    // coarse-bucket LDS capacity (N <= 102400)

typedef __attribute__((ext_vector_type(8))) short bf16x8;
typedef __attribute__((ext_vector_type(4))) float f32x4;
typedef __attribute__((ext_vector_type(2))) float f32x2;

__device__ __forceinline__ unsigned bf16_rne(float f) {
  unsigned u = __float_as_uint(f);
  return (u + 0x7FFFu + ((u >> 16) & 1u)) >> 16;
}
__device__ __forceinline__ unsigned pack2(float a, float b) {
  return bf16_rne(a) | (bf16_rne(b) << 16);
}
__device__ __forceinline__ float bf16lo(unsigned u) { return __uint_as_float(u << 16); }
__device__ __forceinline__ float bf16hi(unsigned u) { return __uint_as_float(u & 0xFFFF0000u); }
__device__ __forceinline__ float bf16s(unsigned short v) { return __uint_as_float(((unsigned)v) << 16); }

// x fp32 -> xh bf16 (packed pairs) + xq fp8 e4m3 (packed quads)
__global__ __launch_bounds__(256) void k_cvt(const float4* __restrict__ x,
                                             uint2* __restrict__ xh,
                                             unsigned* __restrict__ xq, int n4) {
  int stride = gridDim.x * 256;
  for (int i = blockIdx.x * 256 + threadIdx.x; i < n4; i += stride) {
    float4 v = x[i];
    xh[i] = make_uint2(pack2(v.x, v.y), pack2(v.z, v.w));
    unsigned q = __builtin_amdgcn_cvt_pk_fp8_f32(v.x, v.y, 0u, false);
    q = __builtin_amdgcn_cvt_pk_fp8_f32(v.z, v.w, q, true);
    xq[i] = q;
  }
}

// W (fp32) -> split-bf16 B-fragments in MFMA order:
// p[((kt*8+ct)*64 + lane)*8 + j] = Wcat[kt*32 + (lane>>4)*8 + j][ct*16 + (lane&15)]
__global__ __launch_bounds__(256) void k_wprep(const float* __restrict__ W1l,
                                               const float* __restrict__ W1r,
                                               const float* __restrict__ W2l,
                                               const float* __restrict__ W2r,
                                               unsigned short* __restrict__ p1h,
                                               unsigned short* __restrict__ p1l,
                                               unsigned short* __restrict__ p2h,
                                               unsigned short* __restrict__ p2l) {
  int idx = blockIdx.x * 256 + threadIdx.x;
  if (idx < 32768) {
    int j = idx & 7, l = (idx >> 3) & 63, ct = (idx >> 9) & 7, kt = idx >> 12;
    int k = kt * 32 + (l >> 4) * 8 + j;
    int c = ct * 16 + (l & 15);
    float wv = (k < 128) ? W1l[k * 128 + c] : W1r[(k - 128) * 128 + c];
    unsigned short hi = (unsigned short)bf16_rne(wv);
    float hif = __uint_as_float(((unsigned)hi) << 16);
    unsigned short lo = (unsigned short)bf16_rne(wv - hif);
    p1h[idx] = hi; p1l[idx] = lo;
  } else if (idx < 49152) {
    int i2 = idx - 32768;
    int j = i2 & 7, l = (i2 >> 3) & 63, ct = (i2 >> 9) & 7, kt = i2 >> 12;
    int k = kt * 32 + (l >> 4) * 8 + j;
    int c = ct * 16 + (l & 15);
    float wv = (c < 64) ? W2l[k * 64 + c] : W2r[k * 64 + (c - 64)];
    unsigned short hi = (unsigned short)bf16_rne(wv);
    float hif = __uint_as_float(((unsigned)hi) << 16);
    unsigned short lo = (unsigned short)bf16_rne(wv - hif);
    p2h[i2] = hi; p2l[i2] = lo;
  }
}

// 1) per-block LDS coarse histogram (NG buckets); coalesced flush
__global__ __launch_bounds__(256) void k_hist1(const int* __restrict__ dst,
                                               int* __restrict__ histG,
                                               int NG, int E) {
  __shared__ int h[NG_MAX];
  for (int i = threadIdx.x; i < NG; i += 256) h[i] = 0;
  __syncthreads();
  for (int c = blockIdx.x; c * CHUNK < E; c += gridDim.x) {
    int e0 = c * CHUNK, e1 = min(e0 + CHUNK, E);
    for (int e = e0 + threadIdx.x; e < e1; e += 256)
      atomicAdd(&h[dst[e] >> 8], 1);
  }
  __syncthreads();
  for (int i = threadIdx.x; i < NG; i += 256) histG[blockIdx.x * NG + i] = h[i];
}

// bucket totals (rows coalesced across b)
__global__ __launch_bounds__(256) void k_btot(const int* __restrict__ histG,
                                              int* __restrict__ btot, int NG) {
  int b = blockIdx.x * 256 + threadIdx.x;
  if (b >= NG) return;
  int s = 0;
  for (int k = 0; k < P1B; ++k) s += histG[k * NG + b];
  btot[b] = s;
}

// single-block exclusive scan of NG (<=512) bucket totals -> goff[0..NG]
__global__ void k_gscan(const int* __restrict__ btot, int* __restrict__ goff,
                        int ng, int E) {
  __shared__ int sh[512];
  int t = threadIdx.x;
  int v = (t < ng) ? btot[t] : 0;
  sh[t] = v;
  __syncthreads();
  int x = v;
  for (int d = 1; d < 512; d <<= 1) {
    int y = (t >= d) ? sh[t - d] : 0;
    __syncthreads();
    x += y;
    sh[t] = x;
    __syncthreads();
  }
  if (t < ng) goff[t] = x - v;
  if (t == 0) goff[ng] = E;
}

// per-(block,bucket) slice starts
__global__ __launch_bounds__(256) void k_scur(const int* __restrict__ goff,
                                              const int* __restrict__ histG,
                                              int* __restrict__ S2, int NG) {
  int b = blockIdx.x * 256 + threadIdx.x;
  if (b >= NG) return;
  int run = goff[b];
  for (int k = 0; k < P1B; ++k) {
    S2[k * NG + b] = run;
    run += histG[k * NG + b];
  }
}

// 3) scatter into private per-(block,bucket) slices; LDS cursors only.
// Chunk partition MUST match k_hist1 (same grid, same CHUNK).
__global__ __launch_bounds__(256) void k_part1(const int* __restrict__ src,
                                               const int* __restrict__ dst,
                                               const int* __restrict__ S2,
                                               unsigned* __restrict__ tmp,
                                               int NG, int E) {
  __shared__ int cur[NG_MAX];
  for (int i = threadIdx.x; i < NG; i += 256) cur[i] = S2[blockIdx.x * NG + i];
  __syncthreads();
  for (int c = blockIdx.x; c * CHUNK < E; c += gridDim.x) {
    int e0 = c * CHUNK, e1 = min(e0 + CHUNK, E);
    for (int e = e0 + threadIdx.x; e < e1; e += 256) {
      int d = dst[e];
      int p = atomicAdd(&cur[d >> 8], 1);
      tmp[p] = (unsigned)src[e] | ((unsigned)(d & 255) << 17); // src < 2^17
    }
  }
}

// 4) block-per-group: count 256 node degrees (LDS) -> block scan -> off[];
//    place pass -> exact CSR slot (writes confined to group's region).
__global__ __launch_bounds__(256) void k_part2(const unsigned* __restrict__ tmp,
                                               const int* __restrict__ goff,
                                               int* __restrict__ off,
                                               int* __restrict__ csr,
                                               int NG, int N, int E) {
  __shared__ int sh[256];
  __shared__ int cur[256];
  int g = blockIdx.x, t = threadIdx.x;
  int s = goff[g], e = goff[g + 1];
  int n0 = g * 256;
  sh[t] = 0;
  __syncthreads();
  for (int i = s + t; i < e; i += 256) atomicAdd(&sh[tmp[i] >> 17], 1);
  __syncthreads();
  int v = sh[t];
  __syncthreads();
  sh[t] = v;
  __syncthreads();
  int x = v;
  for (int d = 1; d < 256; d <<= 1) {
    int y = (t >= d) ? sh[t - d] : 0;
    __syncthreads();
    x += y;
    sh[t] = x;
    __syncthreads();
  }
  int base = s + x - v;  // exclusive prefix within group
  cur[t] = base;
  if (n0 + t < N) off[n0 + t] = base;
  if (g == NG - 1 && t == 0) off[N] = E;
  __syncthreads();
  for (int i = s + t; i < e; i += 256) {
    unsigned u = tmp[i];
    int pos = atomicAdd(&cur[u >> 17], 1);
    csr[pos] = (int)(u & 0x1FFFFu);
  }
}

// wave-per-node mean aggregation of fp8 rows -> M (bf16).
// Lane halves process 2 edges/iter; lane lc (0..31) covers cols 4lc..4lc+3
// via one uint load + 2 cvt_pk. 32-bit addressing (row<<5 uints).
__global__ __launch_bounds__(256) void k_agg128(const unsigned* __restrict__ xq,
                                                const int* __restrict__ off,
                                                const int* __restrict__ csr,
                                                unsigned* __restrict__ M, int n) {
  int lane = threadIdx.x & 63;
  int half = lane >> 5;
  int lc = lane & 31;
  int node = blockIdx.x * 4 + (threadIdx.x >> 6);
  if (node >= n) return;
  int s = off[node], e = off[node + 1];
  f32x2 a01 = {0.f, 0.f}, a23 = {0.f, 0.f}, b01 = {0.f, 0.f}, b23 = {0.f, 0.f};
  int i = s;
  for (; i + 4 <= e; i += 4) {
    int sA = csr[i + half];
    int sB = csr[i + 2 + half];
    unsigned uA = xq[((unsigned)sA << 5) + lc];
    unsigned uB = xq[((unsigned)sB << 5) + lc];
    a01 += __builtin_amdgcn_cvt_pk_f32_fp8(uA, false);
    a23 += __builtin_amdgcn_cvt_pk_f32_fp8(uA, true);
    b01 += __builtin_amdgcn_cvt_pk_f32_fp8(uB, false);
    b23 += __builtin_amdgcn_cvt_pk_f32_fp8(uB, true);
  }
  for (; i + 2 <= e; i += 2) {
    int sA = csr[i + half];
    unsigned uA = xq[((unsigned)sA << 5) + lc];
    a01 += __builtin_amdgcn_cvt_pk_f32_fp8(uA, false);
    a23 += __builtin_amdgcn_cvt_pk_f32_fp8(uA, true);
  }
  if (i < e && half == 0) {  // odd remainder: lanes 0-31 take the last edge
    int sA = csr[i];
    unsigned uA = xq[((unsigned)sA << 5) + lc];
    a01 += __builtin_amdgcn_cvt_pk_f32_fp8(uA, false);
    a23 += __builtin_amdgcn_cvt_pk_f32_fp8(uA, true);
  }
  a01 += b01; a23 += b23;
  float r0 = a01[0] + __shfl_xor(a01[0], 32, 64);
  float r1 = a01[1] + __shfl_xor(a01[1], 32, 64);
  float r2 = a23[0] + __shfl_xor(a23[0], 32, 64);
  float r3 = a23[1] + __shfl_xor(a23[1], 32, 64);
  if (half == 0) {
    int deg = e - s;
    float inv = 1.0f / (float)(deg > 0 ? deg : 1);
    ((uint2*)M)[(size_t)node * 32 + lc] =
        make_uint2(pack2(r0 * inv, r1 * inv), pack2(r2 * inv, r3 * inv));
  }
}

// MFMA GEMM: 1 wave = 16 rows x 128 cols; block = 4 waves = 64 rows.
// RELU=true : C = bf16 [N,128] = relu(A@W + bias)
// RELU=false: cols 0-63 -> Cg fp8 [N,64] (gather table), cols 64-127 ->
//             Cs bf16 [N,64] (self term, full precision)
// Layouts (CDNA4 16x16x32): A row=l&15, k=(l>>4)*8+j; B col=l&15, same k;
// D col=l&15, row=(l>>4)*4+reg  [m89-verified].
template <int KSTEPS, bool TWOA, bool RELU>
__global__ __launch_bounds__(256) void k_mm(const unsigned short* __restrict__ A0,
                                            const unsigned short* __restrict__ A1,
                                            const unsigned short* __restrict__ Bh,
                                            const unsigned short* __restrict__ Bl,
                                            const float* __restrict__ bias,
                                            unsigned short* __restrict__ C,
                                            unsigned char* __restrict__ Cg,
                                            unsigned short* __restrict__ Cs, int N) {
  int l = threadIdx.x & 63, wv = threadIdx.x >> 6;
  int rb = blockIdx.x * 64 + wv * 16;
  int arow = rb + (l & 15);
  if (arow > N - 1) arow = N - 1;                     // clamp: loads stay in-bounds
  const size_t aoff = (size_t)arow * 128 + ((l >> 4) * 8);
  f32x4 acc[8] = {};
  float bs[8];
  if (RELU) {
#pragma unroll
    for (int ct = 0; ct < 8; ++ct) bs[ct] = bias[ct * 16 + (l & 15)];
  }
#pragma unroll 2
  for (int kt = 0; kt < KSTEPS; ++kt) {
    const unsigned short* At = TWOA ? (kt < KSTEPS / 2 ? A0 : A1) : A0;
    int ko = TWOA ? (kt < KSTEPS / 2 ? kt : kt - KSTEPS / 2) : kt;
    bf16x8 a = *(const bf16x8*)(At + aoff + (size_t)ko * 32);
#pragma unroll
    for (int ct = 0; ct < 8; ++ct) {
      bf16x8 bh = *(const bf16x8*)(Bh + (((size_t)(kt * 8 + ct) * 64 + l) * 8));
      bf16x8 bl = *(const bf16x8*)(Bl + (((size_t)(kt * 8 + ct) * 64 + l) * 8));
      acc[ct] = __builtin_amdgcn_mfma_f32_16x16x32_bf16(a, bh, acc[ct], 0, 0, 0);
      acc[ct] = __builtin_amdgcn_mfma_f32_16x16x32_bf16(a, bl, acc[ct], 0, 0, 0);
    }
  }
  int r0 = rb + (l >> 4) * 4;
  int col = l & 15;
#pragma unroll
  for (int ct = 0; ct < 8; ++ct) {
#pragma unroll
    for (int r = 0; r < 4; ++r) {
      int row = r0 + r;
      if (row < N) {
        float v = acc[ct][r];
        if (RELU) {
          v = fmaxf(v + bs[ct], 0.f);
          C[(size_t)row * 128 + ct * 16 + col] = (unsigned short)bf16_rne(v);
        } else {
          if (ct < 4) {
            unsigned q = __builtin_amdgcn_cvt_pk_fp8_f32(v, v, 0u, false);
            Cg[(size_t)row * 64 + ct * 16 + col] = (unsigned char)(q & 0xFF);
          } else {
            Cs[(size_t)row * 64 + (ct - 4) * 16 + col] = (unsigned short)bf16_rne(v);
          }
        }
      }
    }
  }
}

// wave-per-node: mean-gather Pg fp8 (64 B/row). Lane halves process 2
// edges/iter; lane lc covers cols {2lc,2lc+1} via one ushort load + 1 cvt_pk.
// Then + Ps[n]+b2, relu, dot Wfc (f32x2 per lane), 32-lane reduce, sigmoid.
__global__ __launch_bounds__(256) void k_final(const unsigned short* __restrict__ Pg,
                                               const unsigned* __restrict__ Ps,
                                               const int* __restrict__ off,
                                               const int* __restrict__ csr,
                                               const float* __restrict__ b2,
                                               const float* __restrict__ Wfc,
                                               const float* __restrict__ bfc,
                                               float* __restrict__ out, int n) {
  int lane = threadIdx.x & 63;
  int half = lane >> 5;
  int lc = lane & 31;
  int node = blockIdx.x * 4 + (threadIdx.x >> 6);
  if (node >= n) return;
  int s = off[node], e = off[node + 1];
  f32x2 a = {0.f, 0.f}, b = {0.f, 0.f};
  int i = s;
  for (; i + 4 <= e; i += 4) {
    int sA = csr[i + half];
    int sB = csr[i + 2 + half];
    unsigned uA = Pg[((unsigned)sA << 5) + lc];
    unsigned uB = Pg[((unsigned)sB << 5) + lc];
    a += __builtin_amdgcn_cvt_pk_f32_fp8(uA, false);
    b += __builtin_amdgcn_cvt_pk_f32_fp8(uB, false);
  }
  for (; i + 2 <= e; i += 2) {
    int sA = csr[i + half];
    unsigned uA = Pg[((unsigned)sA << 5) + lc];
    a += __builtin_amdgcn_cvt_pk_f32_fp8(uA, false);
  }
  if (i < e && half == 0) {
    int sA = csr[i];
    unsigned uA = Pg[((unsigned)sA << 5) + lc];
    a += __builtin_amdgcn_cvt_pk_f32_fp8(uA, false);
  }
  a += b;
  float r0 = a[0] + __shfl_xor(a[0], 32, 64);
  float r1 = a[1] + __shfl_xor(a[1], 32, 64);
  int deg = e - s;
  float inv = 1.0f / (float)(deg > 0 ? deg : 1);
  unsigned sv = Ps[(size_t)node * 32 + lc];        // cols {2lc, 2lc+1} bf16
  float2 bv = ((const float2*)b2)[lc];
  float2 wv = ((const float2*)Wfc)[lc];
  float h0 = fmaxf(r0 * inv + bf16lo(sv) + bv.x, 0.f);
  float h1 = fmaxf(r1 * inv + bf16hi(sv) + bv.y, 0.f);
  float v = h0 * wv.x + h1 * wv.y;
#pragma unroll
  for (int o2 = 16; o2 > 0; o2 >>= 1) v += __shfl_xor(v, o2, 64);
  if (lane == 0) out[node] = 1.0f / (1.0f + expf(-(v + bfc[0])));
}

extern "C" void kernel_launch(void* const* d_in, const int* in_sizes, int n_in,
                              void* d_out, int out_size, void* d_ws, size_t ws_size,
                              hipStream_t stream) {
  const float* x   = (const float*)d_in[0];
  const int*   ei  = (const int*)d_in[1];
  const float* W1l = (const float*)d_in[2];
  const float* b1  = (const float*)d_in[3];
  const float* W1r = (const float*)d_in[4];
  const float* W2l = (const float*)d_in[5];
  const float* b2  = (const float*)d_in[6];
  const float* W2r = (const float*)d_in[7];
  const float* Wfc = (const float*)d_in[8];
  const float* bfc = (const float*)d_in[9];
  float* out = (float*)d_out;

  const int N = in_sizes[0] / 128;
  const int E = in_sizes[1] / 2;
  const int* srcp = ei;       // edge_index[0]
  const int* dstp = ei + E;   // edge_index[1]
  const int NG = (N + 255) / 256; // 391 <= NG_MAX, <= 512 (gscan capacity)

  // workspace layout (256B aligned regions), ~108 MB total
  char* w = (char*)d_ws;
  auto alloc = [&](size_t bytes) -> void* {
    void* p = (void*)w;
    w += (bytes + 255) & ~(size_t)255;
    return p;
  };
  int*            off   = (int*)alloc((size_t)(N + 1) * 4);
  int*            goff  = (int*)alloc((size_t)(NG + 1) * 4);
  int*            btot  = (int*)alloc((size_t)NG * 4);
  int*            histG = (int*)alloc((size_t)P1B * NG * 4);
  int*            S2    = (int*)alloc((size_t)P1B * NG * 4);
  int*            csr   = (int*)alloc((size_t)E * 4);
  unsigned*       xh    = (unsigned*)alloc((size_t)N * 64 * 4);  // bf16 x (lin_r path)
  unsigned*       xq    = (unsigned*)alloc((size_t)N * 32 * 4);  // fp8 x (mean path)
  unsigned*       M     = (unsigned*)alloc((size_t)N * 64 * 4);  // bf16 agg; later Pg+Ps
  unsigned short* H1b   = (unsigned short*)alloc((size_t)N * 128 * 2);
  unsigned short* p1h   = (unsigned short*)alloc(32768 * 2);
  unsigned short* p1l   = (unsigned short*)alloc(32768 * 2);
  unsigned short* p2h   = (unsigned short*)alloc(16384 * 2);
  unsigned short* p2l   = (unsigned short*)alloc(16384 * 2);
  unsigned* tmp = (unsigned*)H1b;  // lifetimes disjoint: tmp dead before k_mm<8> writes H1b
  // M region (25.6 MB) is dead after k_mm<8> reads it; reuse for Pg (6.4 MB) + Ps (12.8 MB)
  unsigned char*  Pg = (unsigned char*)M;
  unsigned short* Ps = (unsigned short*)((char*)M + (size_t)N * 64);

  const int ngB = (NG + 255) / 256; // 2

  k_cvt<<<1024, 256, 0, stream>>>((const float4*)x, (uint2*)xh, xq, N * 32);
  k_wprep<<<192, 256, 0, stream>>>(W1l, W1r, W2l, W2r, p1h, p1l, p2h, p2l);
  k_hist1<<<P1B, 256, 0, stream>>>(dstp, histG, NG, E);
  k_btot<<<ngB, 256, 0, stream>>>(histG, btot, NG);
  k_gscan<<<1, 512, 0, stream>>>(btot, goff, NG, E);
  k_scur<<<ngB, 256, 0, stream>>>(goff, histG, S2, NG);
  k_part1<<<P1B, 256, 0, stream>>>(srcp, dstp, S2, tmp, NG, E);
  k_part2<<<NG, 256, 0, stream>>>(tmp, goff, off, csr, NG, N, E);
  k_agg128<<<(N + 3) / 4, 256, 0, stream>>>(xq, off, csr, M, N);
  k_mm<8, true, true><<<(N + 63) / 64, 256, 0, stream>>>(
      (const unsigned short*)M, (const unsigned short*)xh, p1h, p1l, b1, H1b,
      nullptr, nullptr, N);
  k_mm<4, false, false><<<(N + 63) / 64, 256, 0, stream>>>(
      H1b, nullptr, p2h, p2l, nullptr, nullptr, Pg, Ps, N);
  k_final<<<(N + 3) / 4, 256, 0, stream>>>((const unsigned short*)Pg, (const unsigned*)Ps,
                                           off, csr, b2, Wfc, bfc, out, N);
}